// Round 1
// baseline (6892.474 us; speedup 1.0000x reference)
//
#include <hip/hip_runtime.h>
#include <hip/hip_bf16.h>

using bf16 = __hip_bfloat16;
typedef __attribute__((ext_vector_type(8))) short short8;
typedef __attribute__((ext_vector_type(4))) float f32x4;

#define NTOK 197
#define MTOK 1576   // 8*197
#define MPATCH 1568 // 8*196

static __device__ __forceinline__ float bf2f(bf16 v){ return __bfloat162float(v); }
static __device__ __forceinline__ bf16 f2bf(float v){ return __float2bfloat16(v); }

static __device__ __forceinline__ float gelu_tanh(float x){
  float x3 = x*x*x;
  float a = 0.7978845608028654f*(x + 0.044715f*x3);
  float e = __expf(-2.f*fabsf(a));
  float t = (1.f-e)/(1.f+e);
  t = (a >= 0.f) ? t : -t;
  return 0.5f*x*(1.f+t);
}

// ---------------- generic fp32 -> bf16 convert (by 4) ----------------
__global__ void cvt_k(const float* __restrict__ in, bf16* __restrict__ out, int n4){
  int i = blockIdx.x*256 + threadIdx.x;
  if (i >= n4) return;
  float4 v = *(const float4*)(in + (size_t)i*4);
  union { bf16 b[4]; uint2 u; } r;
  r.b[0]=f2bf(v.x); r.b[1]=f2bf(v.y); r.b[2]=f2bf(v.z); r.b[3]=f2bf(v.w);
  *(uint2*)(out + (size_t)i*4) = r.u;
}

// ---------------- dequant int4-in-int32 -> bf16 (by 4) ----------------
__global__ void dequant_k(const int* __restrict__ q, const float* __restrict__ s,
                          bf16* __restrict__ out, int N, int K){
  int i = blockIdx.x*256 + threadIdx.x;
  int total = (N*K) >> 2;
  if (i >= total) return;
  int e0 = i*4;
  int n = e0 / K, k4 = e0 % K;
  int4 qv = *(const int4*)(q + (size_t)n*K + k4);
  float sc = s[(size_t)n*(K>>6) + (k4>>6)];
  union { bf16 b[4]; uint2 u; } r;
  r.b[0]=f2bf(((float)qv.x - 7.5f)*sc);
  r.b[1]=f2bf(((float)qv.y - 7.5f)*sc);
  r.b[2]=f2bf(((float)qv.z - 7.5f)*sc);
  r.b[3]=f2bf(((float)qv.w - 7.5f)*sc);
  *(uint2*)(out + (size_t)n*K + k4) = r.u;
}

// ---------------- patchify: img (8,1,3,224,224) f32 -> p (1568, 768) bf16 ----------------
__global__ void patchify_k(const float* __restrict__ img, bf16* __restrict__ p){
  int idx = blockIdx.x*256 + threadIdx.x;
  if (idx >= MPATCH*768) return;
  int col = idx % 768, pr = idx / 768;
  int b = pr / 196, patch = pr % 196;
  int c = col >> 8, rem = col & 255, py = rem >> 4, px = rem & 15;
  int gy = patch / 14, gx = patch % 14;
  float v = img[(((size_t)(b*3 + c))*224 + gy*16 + py)*224 + gx*16 + px];
  p[idx] = f2bf(v);
}

// ---------------- assemble x = [cls ; tok] (fp32) ----------------
__global__ void assemble_k(const float* __restrict__ tok, const float* __restrict__ cls,
                           float* __restrict__ x){
  int idx = blockIdx.x*256 + threadIdx.x;
  if (idx >= MTOK*768) return;
  int d = idx % 768, row = idx / 768;
  int b = row / NTOK, r = row % NTOK;
  x[idx] = (r == 0) ? cls[d] : tok[((size_t)(b*196) + r - 1)*768 + d];
}

// ---------------- LayerNorm over D=768, one wave per row, out bf16 ----------------
__global__ __launch_bounds__(256) void ln_k(const float* __restrict__ x,
                                            const float* __restrict__ g,
                                            const float* __restrict__ b,
                                            bf16* __restrict__ out, int M){
  int row = blockIdx.x*4 + (threadIdx.x >> 6);
  int lane = threadIdx.x & 63;
  if (row >= M) return;
  const float* xr = x + (size_t)row*768;
  float v[12]; float s = 0.f;
  #pragma unroll
  for (int i=0;i<12;i++){ v[i] = xr[lane + i*64]; s += v[i]; }
  #pragma unroll
  for (int o=32;o;o>>=1) s += __shfl_xor(s, o);
  float mean = s * (1.f/768.f);
  float vs = 0.f;
  #pragma unroll
  for (int i=0;i<12;i++){ float d = v[i]-mean; vs += d*d; }
  #pragma unroll
  for (int o=32;o;o>>=1) vs += __shfl_xor(vs, o);
  float rs = rsqrtf(vs*(1.f/768.f) + 1e-6f);
  bf16* orow = out + (size_t)row*768;
  #pragma unroll
  for (int i=0;i<12;i++){
    int d0 = lane + i*64;
    orow[d0] = f2bf((v[i]-mean)*rs*g[d0] + b[d0]);
  }
}

// ---------------- residual: x += g[d] * t ----------------
__global__ void resid_k(float* __restrict__ x, const float* __restrict__ t,
                        const float* __restrict__ g){
  int i = blockIdx.x*256 + threadIdx.x;
  if (i >= (MTOK*768)/4) return;
  int d = (i*4) % 768;
  float4 xv = *(float4*)(x + (size_t)i*4);
  float4 tv = *(const float4*)(t + (size_t)i*4);
  float4 gv = *(const float4*)(g + d);
  xv.x += gv.x*tv.x; xv.y += gv.y*tv.y; xv.z += gv.z*tv.z; xv.w += gv.w*tv.w;
  *(float4*)(x + (size_t)i*4) = xv;
}

// ---------------- attention: one block per (b,h), thread = query row, online softmax ----------------
__global__ __launch_bounds__(256) void attn_k(const float* __restrict__ qkv, bf16* __restrict__ o){
  __shared__ bf16 kk[NTOK][64];
  __shared__ bf16 vv[NTOK][64];
  int bh = blockIdx.x; int b = bh / 12, h = bh % 12;
  int t = threadIdx.x;
  const float* base = qkv + (size_t)b*NTOK*2304 + h*64;
  for (int idx = t; idx < NTOK*64; idx += 256){
    int m = idx >> 6, d = idx & 63;
    kk[m][d] = f2bf(base[(size_t)m*2304 + 768 + d]);
    vv[m][d] = f2bf(base[(size_t)m*2304 + 1536 + d]);
  }
  __syncthreads();
  if (t >= NTOK) return;
  float q[64];
  const float* qrow = base + (size_t)t*2304;
  #pragma unroll
  for (int d=0; d<64; d++) q[d] = qrow[d]*0.125f;
  float mrun = -1e30f, srun = 0.f;
  float acc[64];
  #pragma unroll
  for (int d=0; d<64; d++) acc[d] = 0.f;
  for (int m=0; m<NTOK; m++){
    float dot = 0.f;
    #pragma unroll
    for (int d=0; d<64; d++) dot += q[d]*bf2f(kk[m][d]);
    if (dot > mrun){
      float sc = __expf(mrun - dot);
      srun *= sc;
      #pragma unroll
      for (int d=0; d<64; d++) acc[d] *= sc;
      mrun = dot;
    }
    float w = __expf(dot - mrun);
    srun += w;
    #pragma unroll
    for (int d=0; d<64; d++) acc[d] += w*bf2f(vv[m][d]);
  }
  float inv = 1.f/srun;
  bf16* orow = o + ((size_t)(b*NTOK) + t)*768 + h*64;
  #pragma unroll
  for (int d=0; d<64; d++) orow[d] = f2bf(acc[d]*inv);
}

// ---------------- mean-pool tokens 1..196 ----------------
__global__ void pool_k(const float* __restrict__ x, float* __restrict__ pooled){
  int idx = blockIdx.x*256 + threadIdx.x;
  if (idx >= 8*768) return;
  int b = idx / 768, d = idx % 768;
  float s = 0.f;
  for (int i=1;i<NTOK;i++) s += x[((size_t)(b*NTOK)+i)*768 + d];
  pooled[idx] = s * (1.f/196.f);
}

// ---------------- MFMA GEMM: C[M,N] = act( alpha * A[M,K] @ W[N,K]^T + bias (+C) ) ----------------
// A, W bf16 row-major. OUT_BF16: store bf16 else fp32. ACT: 0 none, 1 gelu, 2 relu. ACCUM: C += (fp32 only).
template<int OUT_BF16, int ACT, int ACCUM>
__global__ __launch_bounds__(256) void gemm_bt(const bf16* __restrict__ A,
                                               const bf16* __restrict__ W,
                                               const float* __restrict__ bias,
                                               void* __restrict__ Cout,
                                               int M, int N, int K, float alpha){
  __shared__ char As[128*128];  // 128 rows x 64 bf16 (128B/row), XOR-swizzled
  __shared__ char Ws[128*128];
  const int mt = blockIdx.x, nt = blockIdx.y;
  const int t = threadIdx.x;
  const int wave = t >> 6, lane = t & 63;
  const int wr = wave >> 1, wc = wave & 1;

  f32x4 acc[4][4];
  #pragma unroll
  for (int i=0;i<4;i++)
    #pragma unroll
    for (int j=0;j<4;j++) acc[i][j] = (f32x4){0.f,0.f,0.f,0.f};

  const int sr = t >> 3;            // 0..31
  const int sc8 = (t & 7) * 8;      // element col (8 bf16 = 16B)

  for (int k0 = 0; k0 < K; k0 += 64){
    #pragma unroll
    for (int i=0;i<4;i++){
      int r = sr + 32*i;
      int cb = (sc8*2) ^ ((r & 7) << 4);
      uint4 av = {0,0,0,0};
      int gm = mt*128 + r;
      if (gm < M) av = *(const uint4*)(A + (size_t)gm*K + k0 + sc8);
      *(uint4*)(As + r*128 + cb) = av;
      uint4 wv = {0,0,0,0};
      int gn = nt*128 + r;
      if (gn < N) wv = *(const uint4*)(W + (size_t)gn*K + k0 + sc8);
      *(uint4*)(Ws + r*128 + cb) = wv;
    }
    __syncthreads();
    const int lrow = lane & 15, lk = (lane >> 4) * 8;
    #pragma unroll
    for (int kk=0; kk<64; kk+=32){
      short8 af[4], bfm[4];
      #pragma unroll
      for (int f=0; f<4; f++){
        int ra = wr*64 + f*16 + lrow;
        af[f] = *(const short8*)(As + ra*128 + (((kk + lk)*2) ^ ((ra & 7) << 4)));
        int rb = wc*64 + f*16 + lrow;
        bfm[f] = *(const short8*)(Ws + rb*128 + (((kk + lk)*2) ^ ((rb & 7) << 4)));
      }
      #pragma unroll
      for (int i=0;i<4;i++)
        #pragma unroll
        for (int j=0;j<4;j++)
          acc[i][j] = __builtin_amdgcn_mfma_f32_16x16x32_bf16(af[i], bfm[j], acc[i][j], 0, 0, 0);
    }
    __syncthreads();
  }

  const int erow = (lane >> 4) * 4, ecol = lane & 15;
  #pragma unroll
  for (int i=0;i<4;i++){
    #pragma unroll
    for (int j=0;j<4;j++){
      int n = nt*128 + wc*64 + j*16 + ecol;
      float bv = (bias != nullptr && n < N) ? bias[n] : 0.f;
      #pragma unroll
      for (int qi=0; qi<4; qi++){
        int m = mt*128 + wr*64 + i*16 + erow + qi;
        if (m < M && n < N){
          float v = acc[i][j][qi]*alpha + bv;
          size_t off = (size_t)m*N + n;
          if (ACCUM) v += ((float*)Cout)[off];
          if (ACT == 1) v = gelu_tanh(v);
          if (ACT == 2) v = fmaxf(v, 0.f);
          if (OUT_BF16) ((bf16*)Cout)[off] = f2bf(v);
          else          ((float*)Cout)[off] = v;
        }
      }
    }
  }
}

// ===================================================================
extern "C" void kernel_launch(void* const* d_in, const int* in_sizes, int n_in,
                              void* d_out, int out_size, void* d_ws, size_t ws_size,
                              hipStream_t stream){
  (void)in_sizes; (void)n_in; (void)out_size; (void)ws_size;
  const float* img    = (const float*)d_in[0];
  const float* patchw = (const float*)d_in[1];
  const float* patchb = (const float*)d_in[2];
  const float* cls    = (const float*)d_in[3];
  const float* ln1g   = (const float*)d_in[4];
  const float* ln1b   = (const float*)d_in[5];
  const float* ln2g   = (const float*)d_in[6];
  const float* ln2b   = (const float*)d_in[7];
  const float* g1     = (const float*)d_in[8];
  const float* g2     = (const float*)d_in[9];
  const int*   qkvq   = (const int*)d_in[10];
  const float* qkvs   = (const float*)d_in[11];
  const float* qkvb   = (const float*)d_in[12];
  const float* aQ     = (const float*)d_in[13];
  const float* bQ     = (const float*)d_in[14];
  const int*   projq  = (const int*)d_in[15];
  const float* projs  = (const float*)d_in[16];
  const float* projb  = (const float*)d_in[17];
  const float* aP     = (const float*)d_in[18];
  const float* bP     = (const float*)d_in[19];
  const int*   fc1q   = (const int*)d_in[20];
  const float* fc1s   = (const float*)d_in[21];
  const float* fc1b   = (const float*)d_in[22];
  const int*   fc2q   = (const int*)d_in[23];
  const float* fc2s   = (const float*)d_in[24];
  const float* fc2b   = (const float*)d_in[25];
  const float* fcng   = (const float*)d_in[26];
  const float* fcnb   = (const float*)d_in[27];
  const float* headw  = (const float*)d_in[28];
  const float* headb  = (const float*)d_in[29];
  float* out = (float*)d_out;

  char* wp = (char*)d_ws;
  auto alloc = [&](size_t bytes)->char* {
    char* r = wp; wp += (bytes + 255) & ~(size_t)255; return r;
  };
  float* x      = (float*)alloc((size_t)MTOK*768*4);
  float* tmp    = (float*)alloc((size_t)MTOK*768*4);
  float* qkv    = (float*)alloc((size_t)MTOK*2304*4);
  bf16*  h      = (bf16*) alloc((size_t)MTOK*768*2);
  bf16*  h1     = (bf16*) alloc((size_t)MTOK*3072*2);
  bf16*  ob     = (bf16*) alloc((size_t)MTOK*768*2);
  bf16*  u      = (bf16*) alloc((size_t)MTOK*64*2);
  bf16*  p      = (bf16*) alloc((size_t)MPATCH*768*2);
  bf16*  Wqkv   = (bf16*) alloc((size_t)2304*768*2);
  bf16*  Wproj  = (bf16*) alloc((size_t)768*768*2);
  bf16*  Wfc1   = (bf16*) alloc((size_t)3072*768*2);
  bf16*  Wfc2   = (bf16*) alloc((size_t)3072*768*2);
  bf16*  pwb    = (bf16*) alloc((size_t)768*768*2);
  bf16*  hwb    = (bf16*) alloc((size_t)512*768*2);
  bf16*  aQb    = (bf16*) alloc((size_t)12*64*768*2);
  bf16*  bQb    = (bf16*) alloc((size_t)12*2304*64*2);
  bf16*  aPb    = (bf16*) alloc((size_t)12*64*768*2);
  bf16*  bPb    = (bf16*) alloc((size_t)12*768*64*2);
  float* pooled = (float*)alloc((size_t)8*768*4);
  bf16*  pooledb= (bf16*) alloc((size_t)8*768*2);

  auto cvt = [&](const float* in, bf16* o, size_t n){
    int n4 = (int)(n/4);
    cvt_k<<<(n4+255)/256, 256, 0, stream>>>(in, o, n4);
  };
  cvt(patchw, pwb, (size_t)768*768);
  cvt(headw,  hwb, (size_t)512*768);
  cvt(aQ, aQb, (size_t)12*64*768);
  cvt(bQ, bQb, (size_t)12*2304*64);
  cvt(aP, aPb, (size_t)12*64*768);
  cvt(bP, bPb, (size_t)12*768*64);

  patchify_k<<<(MPATCH*768 + 255)/256, 256, 0, stream>>>(img, p);
  // tok = p @ patch_w^T + patch_b  -> tmp (fp32)
  gemm_bt<0,0,0><<<dim3((MPATCH+127)/128, 768/128), 256, 0, stream>>>(
      p, pwb, patchb, tmp, MPATCH, 768, 768, 1.f);
  assemble_k<<<(MTOK*768 + 255)/256, 256, 0, stream>>>(tmp, cls, x);

  for (int l=0; l<12; l++){
    // dequant this layer's weights
    dequant_k<<<((2304*768/4)+255)/256, 256, 0, stream>>>(
        qkvq + (size_t)l*2304*768, qkvs + (size_t)l*2304*12, Wqkv, 2304, 768);
    dequant_k<<<((768*768/4)+255)/256, 256, 0, stream>>>(
        projq + (size_t)l*768*768, projs + (size_t)l*768*12, Wproj, 768, 768);
    dequant_k<<<((3072*768/4)+255)/256, 256, 0, stream>>>(
        fc1q + (size_t)l*3072*768, fc1s + (size_t)l*3072*12, Wfc1, 3072, 768);
    dequant_k<<<((768*3072/4)+255)/256, 256, 0, stream>>>(
        fc2q + (size_t)l*768*3072, fc2s + (size_t)l*768*48, Wfc2, 768, 3072);

    // h = LN1(x)
    ln_k<<<(MTOK+3)/4, 256, 0, stream>>>(x, ln1g + l*768, ln1b + l*768, h, MTOK);
    // qkv = h @ Wqkv^T + qkv_b
    gemm_bt<0,0,0><<<dim3((MTOK+127)/128, 2304/128), 256, 0, stream>>>(
        h, Wqkv, qkvb + (size_t)l*2304, qkv, MTOK, 2304, 768, 1.f);
    // u = h @ aQ^T (bf16)
    gemm_bt<1,0,0><<<dim3((MTOK+127)/128, 1), 256, 0, stream>>>(
        h, aQb + (size_t)l*64*768, (const float*)nullptr, u, MTOK, 64, 768, 1.f);
    // qkv += 0.25 * u @ bQ^T
    gemm_bt<0,0,1><<<dim3((MTOK+127)/128, 2304/128), 256, 0, stream>>>(
        u, bQb + (size_t)l*2304*64, (const float*)nullptr, qkv, MTOK, 2304, 64, 0.25f);
    // attention -> ob (bf16)
    attn_k<<<96, 256, 0, stream>>>(qkv, ob);
    // tmp = ob @ Wproj^T + proj_b
    gemm_bt<0,0,0><<<dim3((MTOK+127)/128, 768/128), 256, 0, stream>>>(
        ob, Wproj, projb + (size_t)l*768, tmp, MTOK, 768, 768, 1.f);
    // u = ob @ aP^T ; tmp += 0.25 * u @ bP^T
    gemm_bt<1,0,0><<<dim3((MTOK+127)/128, 1), 256, 0, stream>>>(
        ob, aPb + (size_t)l*64*768, (const float*)nullptr, u, MTOK, 64, 768, 1.f);
    gemm_bt<0,0,1><<<dim3((MTOK+127)/128, 768/128), 256, 0, stream>>>(
        u, bPb + (size_t)l*768*64, (const float*)nullptr, tmp, MTOK, 768, 64, 0.25f);
    // x += g1 * tmp
    resid_k<<<((MTOK*768/4)+255)/256, 256, 0, stream>>>(x, tmp, g1 + l*768);

    // h = LN2(x); h1 = gelu(h @ Wfc1^T + fc1_b); tmp = h1 @ Wfc2^T + fc2_b; x += g2*tmp
    ln_k<<<(MTOK+3)/4, 256, 0, stream>>>(x, ln2g + l*768, ln2b + l*768, h, MTOK);
    gemm_bt<1,1,0><<<dim3((MTOK+127)/128, 3072/128), 256, 0, stream>>>(
        h, Wfc1, fc1b + (size_t)l*3072, h1, MTOK, 3072, 768, 1.f);
    gemm_bt<0,0,0><<<dim3((MTOK+127)/128, 768/128), 256, 0, stream>>>(
        h1, Wfc2, fc2b + (size_t)l*768, tmp, MTOK, 768, 3072, 1.f);
    resid_k<<<((MTOK*768/4)+255)/256, 256, 0, stream>>>(x, tmp, g2 + l*768);
  }

  pool_k<<<(8*768 + 255)/256, 256, 0, stream>>>(x, pooled);
  ln_k<<<2, 256, 0, stream>>>(pooled, fcng, fcnb, pooledb, 8);
  // out = relu(pooled_ln @ head_w^T + head_b)
  gemm_bt<0,2,0><<<dim3(1, 512/128), 256, 0, stream>>>(
      pooledb, hwb, headb, out, 8, 512, 768, 1.f);
}

// Round 2
// 4870.048 us; speedup vs baseline: 1.4153x; 1.4153x over previous
//
#include <hip/hip_runtime.h>
#include <hip/hip_bf16.h>

using bf16 = __hip_bfloat16;
typedef __attribute__((ext_vector_type(8))) short short8;
typedef __attribute__((ext_vector_type(4))) float f32x4;

#define NTOK 197
#define MTOK 1576   // 8*197
#define MPATCH 1568 // 8*196

static __device__ __forceinline__ float bf2f(bf16 v){ return __bfloat162float(v); }
static __device__ __forceinline__ bf16 f2bf(float v){ return __float2bfloat16(v); }
static __device__ __forceinline__ unsigned pk2(float a, float b){
  union{ bf16 h[2]; unsigned u; } r; r.h[0]=f2bf(a); r.h[1]=f2bf(b); return r.u;
}

static __device__ __forceinline__ float gelu_tanh(float x){
  float x3 = x*x*x;
  float a = 0.7978845608028654f*(x + 0.044715f*x3);
  float e = __expf(-2.f*fabsf(a));
  float t = (1.f-e)/(1.f+e);
  t = (a >= 0.f) ? t : -t;
  return 0.5f*x*(1.f+t);
}

// ---------------- patchify: img (8,1,3,224,224) f32 -> p (1568, 768) bf16 ----------------
__global__ void patchify_k(const float* __restrict__ img, bf16* __restrict__ p){
  int idx = blockIdx.x*256 + threadIdx.x;
  if (idx >= MPATCH*768) return;
  int col = idx % 768, pr = idx / 768;
  int b = pr / 196, patch = pr % 196;
  int c = col >> 8, rem = col & 255, py = rem >> 4, px = rem & 15;
  int gy = patch / 14, gx = patch % 14;
  float v = img[(((size_t)(b*3 + c))*224 + gy*16 + py)*224 + gx*16 + px];
  p[idx] = f2bf(v);
}

// ---------------- assemble x = [cls ; tok] (fp32) ----------------
__global__ void assemble_k(const float* __restrict__ tok, const float* __restrict__ cls,
                           float* __restrict__ x){
  int idx = blockIdx.x*256 + threadIdx.x;
  if (idx >= MTOK*768) return;
  int d = idx % 768, row = idx / 768;
  int b = row / NTOK, r = row % NTOK;
  x[idx] = (r == 0) ? cls[d] : tok[((size_t)(b*196) + r - 1)*768 + d];
}

// ---------------- LayerNorm over D=768, one wave per row, out bf16 ----------------
__global__ __launch_bounds__(256) void ln_k(const float* __restrict__ x,
                                            const float* __restrict__ g,
                                            const float* __restrict__ b,
                                            bf16* __restrict__ out, int M){
  int row = blockIdx.x*4 + (threadIdx.x >> 6);
  int lane = threadIdx.x & 63;
  if (row >= M) return;
  const float* xr = x + (size_t)row*768;
  float v[12]; float s = 0.f;
  #pragma unroll
  for (int i=0;i<12;i++){ v[i] = xr[lane + i*64]; s += v[i]; }
  #pragma unroll
  for (int o=32;o;o>>=1) s += __shfl_xor(s, o);
  float mean = s * (1.f/768.f);
  float vs = 0.f;
  #pragma unroll
  for (int i=0;i<12;i++){ float d = v[i]-mean; vs += d*d; }
  #pragma unroll
  for (int o=32;o;o>>=1) vs += __shfl_xor(vs, o);
  float rs = rsqrtf(vs*(1.f/768.f) + 1e-6f);
  bf16* orow = out + (size_t)row*768;
  #pragma unroll
  for (int i=0;i<12;i++){
    int d0 = lane + i*64;
    orow[d0] = f2bf((v[i]-mean)*rs*g[d0] + b[d0]);
  }
}

// ---------------- attention: one block per (b,h), thread = query row, online softmax ----------------
__global__ __launch_bounds__(256) void attn_k(const float* __restrict__ qkv, bf16* __restrict__ o){
  __shared__ bf16 kk[NTOK][64];
  __shared__ bf16 vv[NTOK][64];
  int bh = blockIdx.x; int b = bh / 12, h = bh % 12;
  int t = threadIdx.x;
  const float* base = qkv + (size_t)b*NTOK*2304 + h*64;
  for (int idx = t; idx < NTOK*64; idx += 256){
    int m = idx >> 6, d = idx & 63;
    kk[m][d] = f2bf(base[(size_t)m*2304 + 768 + d]);
    vv[m][d] = f2bf(base[(size_t)m*2304 + 1536 + d]);
  }
  __syncthreads();
  if (t >= NTOK) return;
  float q[64];
  const float* qrow = base + (size_t)t*2304;
  #pragma unroll
  for (int d=0; d<64; d++) q[d] = qrow[d]*0.125f;
  float mrun = -1e30f, srun = 0.f;
  float acc[64];
  #pragma unroll
  for (int d=0; d<64; d++) acc[d] = 0.f;
  for (int m=0; m<NTOK; m++){
    float dot = 0.f;
    #pragma unroll
    for (int d=0; d<64; d++) dot += q[d]*bf2f(kk[m][d]);
    if (dot > mrun){
      float sc = __expf(mrun - dot);
      srun *= sc;
      #pragma unroll
      for (int d=0; d<64; d++) acc[d] *= sc;
      mrun = dot;
    }
    float w = __expf(dot - mrun);
    srun += w;
    #pragma unroll
    for (int d=0; d<64; d++) acc[d] += w*bf2f(vv[m][d]);
  }
  float inv = 1.f/srun;
  bf16* orow = o + ((size_t)(b*NTOK) + t)*768 + h*64;
  #pragma unroll
  for (int d=0; d<64; d++) orow[d] = f2bf(acc[d]*inv);
}

// ---------------- mean-pool tokens 1..196 ----------------
__global__ void pool_k(const float* __restrict__ x, float* __restrict__ pooled){
  int idx = blockIdx.x*256 + threadIdx.x;
  if (idx >= 8*768) return;
  int b = idx / 768, d = idx % 768;
  float s = 0.f;
  for (int i=1;i<NTOK;i++) s += x[((size_t)(b*NTOK)+i)*768 + d];
  pooled[idx] = s * (1.f/196.f);
}

// ==================================================================
// Fused GEMM: C[M,N] = epi( A[M,K]bf16 @ dq(W)[N,K]^T + bias [+ lora] )
//   WTYPE 1: W int32 4-bit + scales[N,K/64]; WTYPE 2: W fp32 * wscale
//   LORA 1: extra K=64 chunk appended: A-part = ulora[M,64] bf16,
//           W-part = 0.25 * Blora[N,64] fp32
//   OUTMODE 0: fp32 store; 1: bf16 store; 2: fp32 resid  C += gvec[n]*v
//   ACT 0 none, 1 gelu, 2 relu
// BM=64 fixed, BK=64, 4 waves as 2x2, double-buffered LDS, prefetch pipeline.
// ==================================================================
template<int BN, int WTYPE, int LORA, int OUTMODE, int ACT>
__global__ __launch_bounds__(256) void gemm_k(
    const bf16* __restrict__ A, const void* __restrict__ W,
    const float* __restrict__ scales, const bf16* __restrict__ ulora,
    const float* __restrict__ Blora, const float* __restrict__ bias,
    const float* __restrict__ gvec, void* __restrict__ Cout,
    int M, int N, int K, float wscale)
{
  constexpr int BM  = 64;
  constexpr int WCN = BN/2;           // wave tile N
  constexpr int FM  = 2;              // 32/16
  constexpr int FN  = WCN/16;
  constexpr int EPT = BN/4;           // W elems per thread per k-iter
  constexpr int TPR = 64/EPT;         // threads per W row
  constexpr int NLD = BN/16;          // uint4 loads (4B-elem types)

  __shared__ char As[2][BM*128];
  __shared__ char Bs[2][BN*128];

  const int mt = blockIdx.x, nt = blockIdx.y;
  const int t = threadIdx.x, wave = t>>6, lane = t&63;
  const int wr = wave>>1, wc = wave&1;
  const int KMAIN = K >> 6;
  const int KT = KMAIN + (LORA ? 1 : 0);

  const int ar0 = t >> 3;             // A stage row (and +32)
  const int acb = (t & 7) << 4;       // A stage byte col
  const int wrow = t / TPR;           // W stage row
  const int wko  = (t % TPR) * EPT;   // W stage elem col
  const int gnw  = nt*BN + wrow;

  f32x4 acc[FM][FN];
  #pragma unroll
  for (int i=0;i<FM;i++)
    #pragma unroll
    for (int j=0;j<FN;j++) acc[i][j] = (f32x4){0.f,0.f,0.f,0.f};

  auto loadA = [&](int it, uint4* av){
    #pragma unroll
    for (int i=0;i<2;i++){
      int gm = mt*BM + ar0 + 32*i; gm = gm < M ? gm : M-1;
      const char* src;
      if (LORA && it == KMAIN) src = (const char*)ulora + (size_t)gm*128 + acb;
      else                     src = (const char*)A + ((size_t)gm*K + ((size_t)it<<6))*2 + acb;
      av[i] = *(const uint4*)src;
    }
  };
  auto writeA = [&](int buf, uint4* av){
    #pragma unroll
    for (int i=0;i<2;i++){
      int r = ar0 + 32*i;
      *(uint4*)(As[buf] + r*128 + (acb ^ ((r&7)<<4))) = av[i];
    }
  };
  auto loadW = [&](int it, uint4* wv, float& sc){
    if (LORA && it == KMAIN){
      const float* fp = Blora + (size_t)gnw*64 + wko;
      #pragma unroll
      for (int c=0;c<NLD;c++) wv[c] = *(const uint4*)(fp + c*4);
      sc = 0.25f;
    } else if (WTYPE == 1){
      const int* qp = (const int*)W + (size_t)gnw*K + (it<<6) + wko;
      #pragma unroll
      for (int c=0;c<NLD;c++) wv[c] = *(const uint4*)(qp + c*4);
      sc = scales[(size_t)gnw*KMAIN + it];
    } else {
      const float* fp = (const float*)W + (size_t)gnw*K + (it<<6) + wko;
      #pragma unroll
      for (int c=0;c<NLD;c++) wv[c] = *(const uint4*)(fp + c*4);
      sc = wscale;
    }
  };
  auto writeW = [&](int buf, uint4* wv, float sc, bool isF){
    #pragma unroll
    for (int c=0;c<EPT/8;c++){
      unsigned pkv[4];
      #pragma unroll
      for (int j=0;j<4;j++){
        unsigned r0 = ((const unsigned*)wv)[c*8 + 2*j];
        unsigned r1 = ((const unsigned*)wv)[c*8 + 2*j + 1];
        float f0 = isF ? __uint_as_float(r0)*sc : ((float)(int)r0 - 7.5f)*sc;
        float f1 = isF ? __uint_as_float(r1)*sc : ((float)(int)r1 - 7.5f)*sc;
        pkv[j] = pk2(f0, f1);
      }
      int cb = (wko + c*8)*2;
      uint4 val; val.x=pkv[0]; val.y=pkv[1]; val.z=pkv[2]; val.w=pkv[3];
      *(uint4*)(Bs[buf] + wrow*128 + (cb ^ ((wrow&7)<<4))) = val;
    }
  };

  { // prologue: stage tile 0 into buf 0
    uint4 av[2]; uint4 wv[NLD]; float sc;
    loadA(0, av); loadW(0, wv, sc);
    writeA(0, av); writeW(0, wv, sc, WTYPE==2);
  }
  __syncthreads();

  const int lrow = lane & 15;
  const int lkb  = (lane >> 4) * 16;  // byte offset within 128B row

  for (int it=0; it<KT; ++it){
    const int buf = it & 1;
    uint4 av[2]; uint4 wv[NLD]; float sc;
    const bool pf = (it+1 < KT);
    if (pf){ loadA(it+1, av); loadW(it+1, wv, sc); }   // issue early (T14)

    #pragma unroll
    for (int kk=0; kk<2; kk++){
      short8 af[FM]; short8 bw[FN];
      #pragma unroll
      for (int f=0; f<FM; f++){
        int ra = wr*32 + f*16 + lrow;
        af[f] = *(const short8*)(As[buf] + ra*128 + ((kk*64 + lkb) ^ ((ra&7)<<4)));
      }
      #pragma unroll
      for (int f=0; f<FN; f++){
        int rb = wc*WCN + f*16 + lrow;
        bw[f] = *(const short8*)(Bs[buf] + rb*128 + ((kk*64 + lkb) ^ ((rb&7)<<4)));
      }
      #pragma unroll
      for (int i=0;i<FM;i++)
        #pragma unroll
        for (int j=0;j<FN;j++)
          acc[i][j] = __builtin_amdgcn_mfma_f32_16x16x32_bf16(af[i], bw[j], acc[i][j], 0, 0, 0);
    }

    if (pf){ writeA(buf^1, av); writeW(buf^1, wv, sc, (WTYPE==2) || (LORA && (it+1)==KMAIN)); }
    __syncthreads();
  }

  // epilogue
  const int erow = (lane >> 4) * 4, ecol = lane & 15;
  #pragma unroll
  for (int i=0;i<FM;i++){
    #pragma unroll
    for (int j=0;j<FN;j++){
      int n = nt*BN + wc*WCN + j*16 + ecol;
      float bv = (bias != nullptr) ? bias[n] : 0.f;
      float gv = (OUTMODE==2) ? gvec[n] : 0.f;
      #pragma unroll
      for (int q=0; q<4; q++){
        int m = mt*BM + wr*32 + i*16 + erow + q;
        if (m < M){
          float v = acc[i][j][q] + bv;
          if (ACT == 1) v = gelu_tanh(v);
          if (ACT == 2) v = fmaxf(v, 0.f);
          size_t off = (size_t)m*N + n;
          if (OUTMODE == 0)      ((float*)Cout)[off] = v;
          else if (OUTMODE == 1) ((bf16*)Cout)[off] = f2bf(v);
          else                   ((float*)Cout)[off] += gv * v;
        }
      }
    }
  }
}

// ===================================================================
extern "C" void kernel_launch(void* const* d_in, const int* in_sizes, int n_in,
                              void* d_out, int out_size, void* d_ws, size_t ws_size,
                              hipStream_t stream){
  (void)in_sizes; (void)n_in; (void)out_size; (void)ws_size;
  const float* img    = (const float*)d_in[0];
  const float* patchw = (const float*)d_in[1];
  const float* patchb = (const float*)d_in[2];
  const float* cls    = (const float*)d_in[3];
  const float* ln1g   = (const float*)d_in[4];
  const float* ln1b   = (const float*)d_in[5];
  const float* ln2g   = (const float*)d_in[6];
  const float* ln2b   = (const float*)d_in[7];
  const float* g1     = (const float*)d_in[8];
  const float* g2     = (const float*)d_in[9];
  const int*   qkvq   = (const int*)d_in[10];
  const float* qkvs   = (const float*)d_in[11];
  const float* qkvb   = (const float*)d_in[12];
  const float* aQ     = (const float*)d_in[13];
  const float* bQ     = (const float*)d_in[14];
  const int*   projq  = (const int*)d_in[15];
  const float* projs  = (const float*)d_in[16];
  const float* projb  = (const float*)d_in[17];
  const float* aP     = (const float*)d_in[18];
  const float* bP     = (const float*)d_in[19];
  const int*   fc1q   = (const int*)d_in[20];
  const float* fc1s   = (const float*)d_in[21];
  const float* fc1b   = (const float*)d_in[22];
  const int*   fc2q   = (const int*)d_in[23];
  const float* fc2s   = (const float*)d_in[24];
  const float* fc2b   = (const float*)d_in[25];
  const float* fcn_g  = (const float*)d_in[26];
  const float* fcn_b  = (const float*)d_in[27];
  const float* headw  = (const float*)d_in[28];
  const float* headb  = (const float*)d_in[29];
  float* out = (float*)d_out;

  char* wp = (char*)d_ws;
  auto alloc = [&](size_t bytes)->char* {
    char* r = wp; wp += (bytes + 255) & ~(size_t)255; return r;
  };
  float* x      = (float*)alloc((size_t)MTOK*768*4);
  float* tmp    = (float*)alloc((size_t)MTOK*768*4);
  float* qkv    = (float*)alloc((size_t)MTOK*2304*4);
  bf16*  h      = (bf16*) alloc((size_t)MTOK*768*2);
  bf16*  h1     = (bf16*) alloc((size_t)MTOK*3072*2);
  bf16*  ob     = (bf16*) alloc((size_t)MTOK*768*2);
  bf16*  u      = (bf16*) alloc((size_t)MTOK*64*2);
  bf16*  p      = (bf16*) alloc((size_t)MPATCH*768*2);
  float* pooled = (float*)alloc((size_t)8*768*4);
  bf16*  pooledb= (bf16*) alloc((size_t)8*768*2);

  const int GM = (MTOK + 63) / 64;   // 25

  patchify_k<<<(MPATCH*768 + 255)/256, 256, 0, stream>>>(img, p);
  // tok = p @ patch_w^T + patch_b  (fp32 W staged directly)
  gemm_k<64,2,0,0,0><<<dim3((MPATCH+63)/64, 768/64), 256, 0, stream>>>(
      p, patchw, nullptr, nullptr, nullptr, patchb, nullptr, tmp,
      MPATCH, 768, 768, 1.f);
  assemble_k<<<(MTOK*768 + 255)/256, 256, 0, stream>>>(tmp, cls, x);

  for (int l=0; l<12; l++){
    const int*   qkvq_l = qkvq + (size_t)l*2304*768;
    const float* qkvs_l = qkvs + (size_t)l*2304*12;
    const int*   projq_l= projq + (size_t)l*768*768;
    const float* projs_l= projs + (size_t)l*768*12;
    const int*   fc1q_l = fc1q + (size_t)l*3072*768;
    const float* fc1s_l = fc1s + (size_t)l*3072*12;
    const int*   fc2q_l = fc2q + (size_t)l*768*3072;
    const float* fc2s_l = fc2s + (size_t)l*768*48;

    // h = LN1(x)
    ln_k<<<(MTOK+3)/4, 256, 0, stream>>>(x, ln1g + l*768, ln1b + l*768, h, MTOK);
    // u = h @ aQ^T (bf16)
    gemm_k<64,2,0,1,0><<<dim3(GM, 1), 256, 0, stream>>>(
        h, aQ + (size_t)l*64*768, nullptr, nullptr, nullptr, nullptr, nullptr, u,
        MTOK, 64, 768, 1.f);
    // qkv = h @ dq(Wqkv)^T + qkv_b + 0.25*u@bQ^T   (LoRA folded as K-extra)
    gemm_k<128,1,1,0,0><<<dim3(GM, 2304/128), 256, 0, stream>>>(
        h, qkvq_l, qkvs_l, u, bQ + (size_t)l*2304*64, qkvb + (size_t)l*2304,
        nullptr, qkv, MTOK, 2304, 768, 1.f);
    // attention -> ob (bf16)
    attn_k<<<96, 256, 0, stream>>>(qkv, ob);
    // u = ob @ aP^T
    gemm_k<64,2,0,1,0><<<dim3(GM, 1), 256, 0, stream>>>(
        ob, aP + (size_t)l*64*768, nullptr, nullptr, nullptr, nullptr, nullptr, u,
        MTOK, 64, 768, 1.f);
    // x += g1 * (ob @ dq(Wproj)^T + proj_b + 0.25*u@bP^T)
    gemm_k<64,1,1,2,0><<<dim3(GM, 768/64), 256, 0, stream>>>(
        ob, projq_l, projs_l, u, bP + (size_t)l*768*64, projb + (size_t)l*768,
        g1 + l*768, x, MTOK, 768, 768, 1.f);

    // h = LN2(x); h1 = gelu(h @ dq(Wfc1)^T + fc1_b)
    ln_k<<<(MTOK+3)/4, 256, 0, stream>>>(x, ln2g + l*768, ln2b + l*768, h, MTOK);
    gemm_k<128,1,0,1,1><<<dim3(GM, 3072/128), 256, 0, stream>>>(
        h, fc1q_l, fc1s_l, nullptr, nullptr, fc1b + (size_t)l*3072,
        nullptr, h1, MTOK, 3072, 768, 1.f);
    // x += g2 * (h1 @ dq(Wfc2)^T + fc2_b)
    gemm_k<64,1,0,2,0><<<dim3(GM, 768/64), 256, 0, stream>>>(
        h1, fc2q_l, fc2s_l, nullptr, nullptr, fc2b + (size_t)l*768,
        g2 + l*768, x, MTOK, 768, 3072, 1.f);
  }

  pool_k<<<(8*768 + 255)/256, 256, 0, stream>>>(x, pooled);
  ln_k<<<2, 256, 0, stream>>>(pooled, fcn_g, fcn_b, pooledb, 8);
  // out = relu(pooled_ln @ head_w^T + head_b)
  gemm_k<128,2,0,0,2><<<dim3(1, 512/128), 256, 0, stream>>>(
      pooledb, headw, nullptr, nullptr, nullptr, headb, nullptr, out,
      8, 512, 768, 1.f);
}

// Round 3
// 3149.550 us; speedup vs baseline: 2.1884x; 1.5463x over previous
//
#include <hip/hip_runtime.h>
#include <hip/hip_bf16.h>

using bf16 = __hip_bfloat16;
typedef __attribute__((ext_vector_type(8))) short short8;
typedef __attribute__((ext_vector_type(4))) float f32x4;

#define NTOK 197
#define MTOK 1576   // 8*197
#define MPATCH 1568 // 8*196
#define UROWS 102400 // 1600*64, one split-K partial slab of u

static __device__ __forceinline__ float bf2f(bf16 v){ return __bfloat162float(v); }
static __device__ __forceinline__ bf16 f2bf(float v){ return __float2bfloat16(v); }
static __device__ __forceinline__ unsigned pk2(float a, float b){
  union{ bf16 h[2]; unsigned u; } r; r.h[0]=f2bf(a); r.h[1]=f2bf(b); return r.u;
}

static __device__ __forceinline__ float gelu_tanh(float x){
  float x3 = x*x*x;
  float a = 0.7978845608028654f*(x + 0.044715f*x3);
  float e = __expf(-2.f*fabsf(a));
  float t = (1.f-e)/(1.f+e);
  t = (a >= 0.f) ? t : -t;
  return 0.5f*x*(1.f+t);
}

// ---------------- patchify: img (8,1,3,224,224) f32 -> p (1568, 768) bf16 ----------------
__global__ void patchify_k(const float* __restrict__ img, bf16* __restrict__ p){
  int idx = blockIdx.x*256 + threadIdx.x;
  if (idx >= MPATCH*768) return;
  int col = idx % 768, pr = idx / 768;
  int b = pr / 196, patch = pr % 196;
  int c = col >> 8, rem = col & 255, py = rem >> 4, px = rem & 15;
  int gy = patch / 14, gx = patch % 14;
  float v = img[(((size_t)(b*3 + c))*224 + gy*16 + py)*224 + gx*16 + px];
  p[idx] = f2bf(v);
}

// ---------------- assemble x = [cls ; tok] (fp32) ----------------
__global__ void assemble_k(const float* __restrict__ tok, const float* __restrict__ cls,
                           float* __restrict__ x){
  int idx = blockIdx.x*256 + threadIdx.x;
  if (idx >= MTOK*768) return;
  int d = idx % 768, row = idx / 768;
  int b = row / NTOK, r = row % NTOK;
  x[idx] = (r == 0) ? cls[d] : tok[((size_t)(b*196) + r - 1)*768 + d];
}

// ---------------- LayerNorm over D=768, one wave per row, float4 loads ----------------
__global__ __launch_bounds__(256) void ln_k(const float* __restrict__ x,
                                            const float* __restrict__ g,
                                            const float* __restrict__ b,
                                            bf16* __restrict__ out, int M){
  int row = blockIdx.x*4 + (threadIdx.x >> 6);
  int lane = threadIdx.x & 63;
  if (row >= M) return;
  const float* xr = x + (size_t)row*768;
  float4 v[3]; float s = 0.f;
  #pragma unroll
  for (int j=0;j<3;j++){
    v[j] = *(const float4*)(xr + lane*4 + j*256);
    s += v[j].x + v[j].y + v[j].z + v[j].w;
  }
  #pragma unroll
  for (int o=32;o;o>>=1) s += __shfl_xor(s, o);
  float mean = s * (1.f/768.f);
  float vs = 0.f;
  #pragma unroll
  for (int j=0;j<3;j++){
    float dx=v[j].x-mean, dy=v[j].y-mean, dz=v[j].z-mean, dw=v[j].w-mean;
    vs += dx*dx + dy*dy + dz*dz + dw*dw;
  }
  #pragma unroll
  for (int o=32;o;o>>=1) vs += __shfl_xor(vs, o);
  float rs = rsqrtf(vs*(1.f/768.f) + 1e-6f);
  bf16* orow = out + (size_t)row*768;
  #pragma unroll
  for (int j=0;j<3;j++){
    int d0 = lane*4 + j*256;
    float4 gv = *(const float4*)(g + d0);
    float4 bv = *(const float4*)(b + d0);
    uint2 pk;
    pk.x = pk2((v[j].x-mean)*rs*gv.x + bv.x, (v[j].y-mean)*rs*gv.y + bv.y);
    pk.y = pk2((v[j].z-mean)*rs*gv.z + bv.z, (v[j].w-mean)*rs*gv.w + bv.w);
    *(uint2*)(orow + d0) = pk;
  }
}

// ---------------- MFMA flash attention ----------------
// grid 192: blk = ((b*12)+h)*2 + half; 4 waves x 32 q-rows; KV chunks of 32.
__global__ __launch_bounds__(256) void attn_k(const bf16* __restrict__ qkv, bf16* __restrict__ o){
  __shared__ char Kc[2][32*128];      // K chunk rows, XOR-swizzled 128B rows
  __shared__ bf16 Vt[2][64][40];      // V chunk transposed [d][kv], padded
  __shared__ bf16 Pl[4][32][40];      // per-wave P, padded

  const int blk = blockIdx.x;
  const int half = blk & 1, bh = blk >> 1;
  const int b = bh / 12, h = bh % 12;
  const int t = threadIdx.x, wave = t>>6, lane = t&63;
  const int qbase = half*128 + wave*32;
  const bf16* base = qkv + (size_t)b*NTOK*2304 + h*64;

  // Q fragments (A-frag layout), 0.125 scale folded into S later
  short8 qf[2][2];
  #pragma unroll
  for (int qt=0;qt<2;qt++){
    int row = qbase + qt*16 + (lane&15); row = row < NTOK ? row : NTOK-1;
    const bf16* qr = base + (size_t)row*2304 + (lane>>4)*8;
    qf[qt][0] = *(const short8*)(qr);
    qf[qt][1] = *(const short8*)(qr + 32);
  }

  f32x4 Oa[2][4];
  float mrow[2][4], srow[2][4];
  #pragma unroll
  for (int i=0;i<2;i++)
    #pragma unroll
    for (int j=0;j<4;j++){ Oa[i][j] = (f32x4){0.f,0.f,0.f,0.f}; }
  #pragma unroll
  for (int i=0;i<2;i++)
    #pragma unroll
    for (int j=0;j<4;j++){ mrow[i][j] = -1e30f; srow[i][j] = 0.f; }

  const int sr = t>>3, sc = (t&7)*8;   // staging: 8 threads/row, 8 elems each
  auto ldK = [&](int c)->uint4{
    int kv = c*32 + sr; kv = kv < NTOK ? kv : NTOK-1;
    return *(const uint4*)(base + (size_t)kv*2304 + 768 + sc);
  };
  auto ldV = [&](int c)->uint4{
    int kv = c*32 + sr;
    uint4 r = {0,0,0,0};
    if (kv < NTOK) r = *(const uint4*)(base + (size_t)kv*2304 + 1536 + sc);
    return r;
  };
  auto wrK = [&](int buf, uint4 kvv){
    *(uint4*)(Kc[buf] + sr*128 + ((sc*2) ^ ((sr&7)<<4))) = kvv;
  };
  auto wrV = [&](int buf, uint4 vvv){
    union{ uint4 u; short s[8]; } w; w.u = vvv;
    #pragma unroll
    for (int j=0;j<8;j++) *(short*)&Vt[buf][sc+j][sr] = w.s[j];
  };

  { uint4 k0 = ldK(0), v0 = ldV(0); wrK(0,k0); wrV(0,v0); }
  __syncthreads();

  for (int c=0;c<7;c++){
    const int buf = c & 1;
    uint4 kn, vn; const bool pf = (c < 6);
    if (pf){ kn = ldK(c+1); vn = ldV(c+1); }   // issue early, write after compute

    // QK^T
    f32x4 S[2][2];
    #pragma unroll
    for (int i=0;i<2;i++)
      #pragma unroll
      for (int j=0;j<2;j++) S[i][j] = (f32x4){0.f,0.f,0.f,0.f};
    #pragma unroll
    for (int kt=0;kt<2;kt++){
      int rk = kt*16 + (lane&15);
      const char* kb = Kc[buf] + rk*128;
      int swz = (rk&7)<<4;
      short8 b0 = *(const short8*)(kb + (((lane>>4)*16) ^ swz));
      short8 b1 = *(const short8*)(kb + ((64 + (lane>>4)*16) ^ swz));
      #pragma unroll
      for (int qt=0;qt<2;qt++){
        S[qt][kt] = __builtin_amdgcn_mfma_f32_16x16x32_bf16(qf[qt][0], b0, S[qt][kt],0,0,0);
        S[qt][kt] = __builtin_amdgcn_mfma_f32_16x16x32_bf16(qf[qt][1], b1, S[qt][kt],0,0,0);
      }
    }

    // online softmax (row state is lane-local per (qt,reg))
    #pragma unroll
    for (int qt=0;qt<2;qt++){
      #pragma unroll
      for (int r=0;r<4;r++){
        float s0 = S[qt][0][r]*0.125f, s1 = S[qt][1][r]*0.125f;
        if (c == 6){
          if (192 + (lane&15) >= NTOK) s0 = -1e30f;
          s1 = -1e30f;                 // kv 208..223 all invalid
        }
        float mx = fmaxf(s0, s1);
        mx = fmaxf(mx, __shfl_xor(mx,1));
        mx = fmaxf(mx, __shfl_xor(mx,2));
        mx = fmaxf(mx, __shfl_xor(mx,4));
        mx = fmaxf(mx, __shfl_xor(mx,8));
        float mo = mrow[qt][r];
        float mn = fmaxf(mo, mx);
        float scl = __expf(mo - mn);
        mrow[qt][r] = mn;
        float p0 = __expf(s0 - mn), p1 = __expf(s1 - mn);
        srow[qt][r] = srow[qt][r]*scl + p0 + p1;   // lane-partial sum; reduced once at end
        #pragma unroll
        for (int dt=0;dt<4;dt++) Oa[qt][dt][r] *= scl;
        int pr = qt*16 + (lane>>4)*4 + r;
        Pl[wave][pr][lane&15]      = f2bf(p0);
        Pl[wave][pr][16+(lane&15)] = f2bf(p1);
      }
    }

    // PV
    short8 vb[4];
    #pragma unroll
    for (int dt=0;dt<4;dt++)
      vb[dt] = *(const short8*)(&Vt[buf][dt*16+(lane&15)][(lane>>4)*8]);
    #pragma unroll
    for (int qt=0;qt<2;qt++){
      short8 pa = *(const short8*)(&Pl[wave][qt*16+(lane&15)][(lane>>4)*8]);
      #pragma unroll
      for (int dt=0;dt<4;dt++)
        Oa[qt][dt] = __builtin_amdgcn_mfma_f32_16x16x32_bf16(pa, vb[dt], Oa[qt][dt],0,0,0);
    }

    if (pf){ wrK(buf^1, kn); wrV(buf^1, vn); }
    __syncthreads();
  }

  // final cross-lane row sums + store
  #pragma unroll
  for (int qt=0;qt<2;qt++)
    #pragma unroll
    for (int r=0;r<4;r++){
      float s = srow[qt][r];
      s += __shfl_xor(s,1); s += __shfl_xor(s,2);
      s += __shfl_xor(s,4); s += __shfl_xor(s,8);
      srow[qt][r] = 1.f/s;
    }
  #pragma unroll
  for (int qt=0;qt<2;qt++){
    #pragma unroll
    for (int r=0;r<4;r++){
      int tok = qbase + qt*16 + (lane>>4)*4 + r;
      if (tok < NTOK){
        bf16* orow = o + ((size_t)(b*NTOK+tok))*768 + h*64 + (lane&15);
        float inv = srow[qt][r];
        #pragma unroll
        for (int dt=0;dt<4;dt++) orow[dt*16] = f2bf(Oa[qt][dt][r]*inv);
      }
    }
  }
}

// ---------------- mean-pool tokens 1..196 ----------------
__global__ void pool_k(const float* __restrict__ x, float* __restrict__ pooled){
  int idx = blockIdx.x*256 + threadIdx.x;
  if (idx >= 8*768) return;
  int b = idx / 768, d = idx % 768;
  float s = 0.f;
  for (int i=1;i<NTOK;i++) s += x[((size_t)(b*NTOK)+i)*768 + d];
  pooled[idx] = s * (1.f/196.f);
}

// ==================================================================
// Fused GEMM: C[M,N] = epi( A[M,K]bf16 @ dq(W)[N,K]^T + bias [+ lora] )
//   WTYPE 1: W int32 4-bit + scales[N,Kst/64]; WTYPE 2: W fp32 * wscale
//   LORA 1: extra K=64 chunk: A-part = sum of 4 fp32 split-K partials of u,
//           W-part = 0.25 * Blora[N,64] fp32
//   OUTMODE 0: fp32 store (+kz*UROWS offset if KSPLIT>1); 1: bf16 store;
//   OUTMODE 2: fp32 resid C += gvec[n]*v.  ACT 0 none, 1 gelu, 2 relu.
//   KSPLIT>1: blockIdx.y = k-slice index (nt=0), k0 = kz*kiters.
// BM=64, BK=64, 4 waves 2x2, double-buffered LDS, reg-prefetch pipeline.
// ==================================================================
template<int BN, int WTYPE, int LORA, int OUTMODE, int ACT, int KSPLIT>
__global__ __launch_bounds__(256) void gemm_k(
    const bf16* __restrict__ A, const void* __restrict__ W,
    const float* __restrict__ scales, const float* __restrict__ upart,
    const float* __restrict__ Blora, const float* __restrict__ bias,
    const float* __restrict__ gvec, void* __restrict__ Cout,
    int M, int N, int Kst, int kiters, float wscale)
{
  constexpr int BM  = 64;
  constexpr int WCN = BN/2;
  constexpr int FM  = 2;
  constexpr int FN  = WCN/16;
  constexpr int EPT = BN/4;           // W elems (4B) per thread per k-iter
  constexpr int TPR = 64/EPT;
  constexpr int NLD = BN/16;

  __shared__ char As[2][BM*128];
  __shared__ char Bs[2][BN*128];

  const int mt = blockIdx.x;
  const int nt = (KSPLIT > 1) ? 0 : blockIdx.y;
  const int kz = (KSPLIT > 1) ? blockIdx.y : 0;
  const int k0 = kz * kiters;
  const int t = threadIdx.x, wave = t>>6, lane = t&63;
  const int wr = wave>>1, wc = wave&1;
  const int KT = kiters + (LORA ? 1 : 0);

  const int ar0 = t >> 3;
  const int acb = (t & 7) << 4;       // byte col in 128B row
  const int wrow = t / TPR;
  const int wko  = (t % TPR) * EPT;
  const int gnw  = nt*BN + wrow;

  f32x4 acc[FM][FN];
  #pragma unroll
  for (int i=0;i<FM;i++)
    #pragma unroll
    for (int j=0;j<FN;j++) acc[i][j] = (f32x4){0.f,0.f,0.f,0.f};

  auto loadA = [&](int it, uint4* av){
    #pragma unroll
    for (int i=0;i<2;i++){
      int gm = mt*BM + ar0 + 32*i; gm = gm < M ? gm : M-1;
      if (LORA && it == kiters){
        const float* up = upart + (size_t)gm*64 + (acb>>1);
        float a[8];
        #pragma unroll
        for (int k=0;k<8;k++) a[k] = 0.f;
        #pragma unroll
        for (int pz=0; pz<4; pz++){
          const float* q = up + (size_t)pz*UROWS;
          float4 x0 = *(const float4*)q;
          float4 x1 = *(const float4*)(q+4);
          a[0]+=x0.x; a[1]+=x0.y; a[2]+=x0.z; a[3]+=x0.w;
          a[4]+=x1.x; a[5]+=x1.y; a[6]+=x1.z; a[7]+=x1.w;
        }
        uint4 r; r.x=pk2(a[0],a[1]); r.y=pk2(a[2],a[3]);
        r.z=pk2(a[4],a[5]); r.w=pk2(a[6],a[7]);
        av[i] = r;
      } else {
        av[i] = *(const uint4*)((const char*)A + ((size_t)gm*Kst + (((size_t)(k0+it))<<6))*2 + acb);
      }
    }
  };
  auto writeA = [&](int buf, uint4* av){
    #pragma unroll
    for (int i=0;i<2;i++){
      int r = ar0 + 32*i;
      *(uint4*)(As[buf] + r*128 + (acb ^ ((r&7)<<4))) = av[i];
    }
  };
  auto loadW = [&](int it, uint4* wv, float& sc){
    if (LORA && it == kiters){
      const float* fp = Blora + (size_t)gnw*64 + wko;
      #pragma unroll
      for (int c=0;c<NLD;c++) wv[c] = *(const uint4*)(fp + c*4);
      sc = 0.25f;
    } else if (WTYPE == 1){
      const int* qp = (const int*)W + (size_t)gnw*Kst + ((k0+it)<<6) + wko;
      #pragma unroll
      for (int c=0;c<NLD;c++) wv[c] = *(const uint4*)(qp + c*4);
      sc = scales[(size_t)gnw*(Kst>>6) + k0 + it];
    } else {
      const float* fp = (const float*)W + (size_t)gnw*Kst + ((k0+it)<<6) + wko;
      #pragma unroll
      for (int c=0;c<NLD;c++) wv[c] = *(const uint4*)(fp + c*4);
      sc = wscale;
    }
  };
  auto writeW = [&](int buf, uint4* wv, float sc, bool isF){
    #pragma unroll
    for (int c=0;c<EPT/8;c++){
      unsigned pkv[4];
      #pragma unroll
      for (int j=0;j<4;j++){
        unsigned r0 = ((const unsigned*)wv)[c*8 + 2*j];
        unsigned r1 = ((const unsigned*)wv)[c*8 + 2*j + 1];
        float f0 = isF ? __uint_as_float(r0)*sc : ((float)(int)r0 - 7.5f)*sc;
        float f1 = isF ? __uint_as_float(r1)*sc : ((float)(int)r1 - 7.5f)*sc;
        pkv[j] = pk2(f0, f1);
      }
      int cb = (wko + c*8)*2;
      uint4 val; val.x=pkv[0]; val.y=pkv[1]; val.z=pkv[2]; val.w=pkv[3];
      *(uint4*)(Bs[buf] + wrow*128 + (cb ^ ((wrow&7)<<4))) = val;
    }
  };

  { // prologue
    uint4 av[2]; uint4 wv[NLD]; float sc;
    loadA(0, av); loadW(0, wv, sc);
    writeA(0, av); writeW(0, wv, sc, WTYPE==2);
  }
  __syncthreads();

  const int lrow = lane & 15;
  const int lkb  = (lane >> 4) * 16;

  for (int it=0; it<KT; ++it){
    const int buf = it & 1;
    uint4 av[2]; uint4 wv[NLD]; float sc;
    const bool pf = (it+1 < KT);
    if (pf){ loadA(it+1, av); loadW(it+1, wv, sc); }

    #pragma unroll
    for (int kk=0; kk<2; kk++){
      short8 af[FM]; short8 bw[FN];
      #pragma unroll
      for (int f=0; f<FM; f++){
        int ra = wr*32 + f*16 + lrow;
        af[f] = *(const short8*)(As[buf] + ra*128 + ((kk*64 + lkb) ^ ((ra&7)<<4)));
      }
      #pragma unroll
      for (int f=0; f<FN; f++){
        int rb = wc*WCN + f*16 + lrow;
        bw[f] = *(const short8*)(Bs[buf] + rb*128 + ((kk*64 + lkb) ^ ((rb&7)<<4)));
      }
      #pragma unroll
      for (int i=0;i<FM;i++)
        #pragma unroll
        for (int j=0;j<FN;j++)
          acc[i][j] = __builtin_amdgcn_mfma_f32_16x16x32_bf16(af[i], bw[j], acc[i][j], 0, 0, 0);
    }

    if (pf){ writeA(buf^1, av); writeW(buf^1, wv, sc, (WTYPE==2) || (LORA && (it+1)==kiters)); }
    __syncthreads();
  }

  // epilogue
  const int erow = (lane >> 4) * 4, ecol = lane & 15;
  #pragma unroll
  for (int i=0;i<FM;i++){
    #pragma unroll
    for (int j=0;j<FN;j++){
      int n = nt*BN + wc*WCN + j*16 + ecol;
      float bv = (bias != nullptr) ? bias[n] : 0.f;
      float gv = (OUTMODE==2) ? gvec[n] : 0.f;
      #pragma unroll
      for (int q=0; q<4; q++){
        int m = mt*BM + wr*32 + i*16 + erow + q;
        if (m < M){
          float v = acc[i][j][q] + bv;
          if (ACT == 1) v = gelu_tanh(v);
          if (ACT == 2) v = fmaxf(v, 0.f);
          size_t off = (size_t)m*N + n;
          if (OUTMODE == 0)      ((float*)Cout)[(size_t)kz*UROWS*(KSPLIT>1) + off] = v;
          else if (OUTMODE == 1) ((bf16*)Cout)[off] = f2bf(v);
          else                   ((float*)Cout)[off] += gv * v;
        }
      }
    }
  }
}

// ===================================================================
extern "C" void kernel_launch(void* const* d_in, const int* in_sizes, int n_in,
                              void* d_out, int out_size, void* d_ws, size_t ws_size,
                              hipStream_t stream){
  (void)in_sizes; (void)n_in; (void)out_size; (void)ws_size;
  const float* img    = (const float*)d_in[0];
  const float* patchw = (const float*)d_in[1];
  const float* patchb = (const float*)d_in[2];
  const float* cls    = (const float*)d_in[3];
  const float* ln1g   = (const float*)d_in[4];
  const float* ln1b   = (const float*)d_in[5];
  const float* ln2g   = (const float*)d_in[6];
  const float* ln2b   = (const float*)d_in[7];
  const float* g1     = (const float*)d_in[8];
  const float* g2     = (const float*)d_in[9];
  const int*   qkvq   = (const int*)d_in[10];
  const float* qkvs   = (const float*)d_in[11];
  const float* qkvb   = (const float*)d_in[12];
  const float* aQ     = (const float*)d_in[13];
  const float* bQ     = (const float*)d_in[14];
  const int*   projq  = (const int*)d_in[15];
  const float* projs  = (const float*)d_in[16];
  const float* projb  = (const float*)d_in[17];
  const float* aP     = (const float*)d_in[18];
  const float* bP     = (const float*)d_in[19];
  const int*   fc1q   = (const int*)d_in[20];
  const float* fc1s   = (const float*)d_in[21];
  const float* fc1b   = (const float*)d_in[22];
  const int*   fc2q   = (const int*)d_in[23];
  const float* fc2s   = (const float*)d_in[24];
  const float* fc2b   = (const float*)d_in[25];
  const float* fcn_g  = (const float*)d_in[26];
  const float* fcn_b  = (const float*)d_in[27];
  const float* headw  = (const float*)d_in[28];
  const float* headb  = (const float*)d_in[29];
  float* out = (float*)d_out;

  char* wp = (char*)d_ws;
  auto alloc = [&](size_t bytes)->char* {
    char* r = wp; wp += (bytes + 255) & ~(size_t)255; return r;
  };
  float* x      = (float*)alloc((size_t)MTOK*768*4);
  float* tmp    = (float*)alloc((size_t)MTOK*768*4);
  bf16*  qkvo   = (bf16*) alloc((size_t)MTOK*2304*2);
  bf16*  h      = (bf16*) alloc((size_t)MTOK*768*2);
  bf16*  h1     = (bf16*) alloc((size_t)MTOK*3072*2);
  bf16*  ob     = (bf16*) alloc((size_t)MTOK*768*2);
  float* u_part = (float*)alloc((size_t)4*UROWS*4);
  bf16*  p      = (bf16*) alloc((size_t)MPATCH*768*2);
  float* pooled = (float*)alloc((size_t)8*768*4);
  bf16*  pooledb= (bf16*) alloc((size_t)8*768*2);

  const int GM = (MTOK + 63) / 64;   // 25

  patchify_k<<<(MPATCH*768 + 255)/256, 256, 0, stream>>>(img, p);
  gemm_k<64,2,0,0,0,1><<<dim3((MPATCH+63)/64, 768/64), 256, 0, stream>>>(
      p, patchw, nullptr, nullptr, nullptr, patchb, nullptr, tmp,
      MPATCH, 768, 768, 12, 1.f);
  assemble_k<<<(MTOK*768 + 255)/256, 256, 0, stream>>>(tmp, cls, x);

  for (int l=0; l<12; l++){
    const int*   qkvq_l = qkvq + (size_t)l*2304*768;
    const float* qkvs_l = qkvs + (size_t)l*2304*12;
    const int*   projq_l= projq + (size_t)l*768*768;
    const float* projs_l= projs + (size_t)l*768*12;
    const int*   fc1q_l = fc1q + (size_t)l*3072*768;
    const float* fc1s_l = fc1s + (size_t)l*3072*12;
    const int*   fc2q_l = fc2q + (size_t)l*768*3072;
    const float* fc2s_l = fc2s + (size_t)l*768*48;

    // h = LN1(x)
    ln_k<<<(MTOK+3)/4, 256, 0, stream>>>(x, ln1g + l*768, ln1b + l*768, h, MTOK);
    // u partials = h @ aQ^T (split-K x4)
    gemm_k<64,2,0,0,0,4><<<dim3(GM, 4), 256, 0, stream>>>(
        h, aQ + (size_t)l*64*768, nullptr, nullptr, nullptr, nullptr, nullptr, u_part,
        MTOK, 64, 768, 3, 1.f);
    // qkv = h @ dq(Wqkv)^T + qkv_b + 0.25*u@bQ^T  (bf16 out)
    gemm_k<128,1,1,1,0,1><<<dim3(GM, 2304/128), 256, 0, stream>>>(
        h, qkvq_l, qkvs_l, u_part, bQ + (size_t)l*2304*64, qkvb + (size_t)l*2304,
        nullptr, qkvo, MTOK, 2304, 768, 12, 1.f);
    // attention -> ob (bf16)
    attn_k<<<192, 256, 0, stream>>>(qkvo, ob);
    // u partials = ob @ aP^T
    gemm_k<64,2,0,0,0,4><<<dim3(GM, 4), 256, 0, stream>>>(
        ob, aP + (size_t)l*64*768, nullptr, nullptr, nullptr, nullptr, nullptr, u_part,
        MTOK, 64, 768, 3, 1.f);
    // x += g1 * (ob @ dq(Wproj)^T + proj_b + 0.25*u@bP^T)
    gemm_k<64,1,1,2,0,1><<<dim3(GM, 768/64), 256, 0, stream>>>(
        ob, projq_l, projs_l, u_part, bP + (size_t)l*768*64, projb + (size_t)l*768,
        g1 + l*768, x, MTOK, 768, 768, 12, 1.f);

    // h = LN2(x); h1 = gelu(h @ dq(Wfc1)^T + fc1_b)
    ln_k<<<(MTOK+3)/4, 256, 0, stream>>>(x, ln2g + l*768, ln2b + l*768, h, MTOK);
    gemm_k<128,1,0,1,1,1><<<dim3(GM, 3072/128), 256, 0, stream>>>(
        h, fc1q_l, fc1s_l, nullptr, nullptr, fc1b + (size_t)l*3072,
        nullptr, h1, MTOK, 3072, 768, 12, 1.f);
    // x += g2 * (h1 @ dq(Wfc2)^T + fc2_b)
    gemm_k<64,1,0,2,0,1><<<dim3(GM, 768/64), 256, 0, stream>>>(
        h1, fc2q_l, fc2s_l, nullptr, nullptr, fc2b + (size_t)l*768,
        g2 + l*768, x, MTOK, 768, 3072, 48, 1.f);
  }

  pool_k<<<(8*768 + 255)/256, 256, 0, stream>>>(x, pooled);
  ln_k<<<2, 256, 0, stream>>>(pooled, fcn_g, fcn_b, pooledb, 8);
  gemm_k<128,2,0,0,2,1><<<dim3(1, 512/128), 256, 0, stream>>>(
      pooledb, headw, nullptr, nullptr, nullptr, headb, nullptr, out,
      8, 512, 768, 12, 1.f);
}

// Round 4
// 2438.582 us; speedup vs baseline: 2.8264x; 1.2915x over previous
//
#include <hip/hip_runtime.h>
#include <hip/hip_bf16.h>

using bf16 = __hip_bfloat16;
typedef __attribute__((ext_vector_type(8))) short short8;
typedef __attribute__((ext_vector_type(4))) float f32x4;

#define NTOK 197
#define MTOK 1576   // 8*197
#define MPATCH 1568 // 8*196
#define UROWS 102400 // 1600*64, one split-K partial slab of u

static __device__ __forceinline__ float bf2f(bf16 v){ return __bfloat162float(v); }
static __device__ __forceinline__ bf16 f2bf(float v){ return __float2bfloat16(v); }
static __device__ __forceinline__ unsigned pk2(float a, float b){
  union{ bf16 h[2]; unsigned u; } r; r.h[0]=f2bf(a); r.h[1]=f2bf(b); return r.u;
}

static __device__ __forceinline__ float gelu_tanh(float x){
  float x3 = x*x*x;
  float a = 0.7978845608028654f*(x + 0.044715f*x3);
  float e = __expf(-2.f*fabsf(a));
  float t = (1.f-e)/(1.f+e);
  t = (a >= 0.f) ? t : -t;
  return 0.5f*x*(1.f+t);
}

// ---------------- pack int4-in-int32 -> nibbles (8 vals per uint32) ----------------
__global__ void pack_k(const int* __restrict__ q, unsigned* __restrict__ o, int n8){
  for (int i = blockIdx.x*256 + threadIdx.x; i < n8; i += gridDim.x*256){
    int4 a = *(const int4*)(q + (size_t)i*8);
    int4 b = *(const int4*)(q + (size_t)i*8 + 4);
    unsigned r = (unsigned)a.x | ((unsigned)a.y<<4) | ((unsigned)a.z<<8) | ((unsigned)a.w<<12)
               | ((unsigned)b.x<<16) | ((unsigned)b.y<<20) | ((unsigned)b.z<<24) | ((unsigned)b.w<<28);
    o[i] = r;
  }
}

// ---------------- patchify: img (8,1,3,224,224) f32 -> p (1568, 768) bf16 ----------------
__global__ void patchify_k(const float* __restrict__ img, bf16* __restrict__ p){
  int idx = blockIdx.x*256 + threadIdx.x;
  if (idx >= MPATCH*768) return;
  int col = idx % 768, pr = idx / 768;
  int b = pr / 196, patch = pr % 196;
  int c = col >> 8, rem = col & 255, py = rem >> 4, px = rem & 15;
  int gy = patch / 14, gx = patch % 14;
  float v = img[(((size_t)(b*3 + c))*224 + gy*16 + py)*224 + gx*16 + px];
  p[idx] = f2bf(v);
}

// ---------------- assemble x = [cls ; tok] (fp32) ----------------
__global__ void assemble_k(const float* __restrict__ tok, const float* __restrict__ cls,
                           float* __restrict__ x){
  int idx = blockIdx.x*256 + threadIdx.x;
  if (idx >= MTOK*768) return;
  int d = idx % 768, row = idx / 768;
  int b = row / NTOK, r = row % NTOK;
  x[idx] = (r == 0) ? cls[d] : tok[((size_t)(b*196) + r - 1)*768 + d];
}

// ---------------- LayerNorm over D=768, one wave per row, float4 loads ----------------
__global__ __launch_bounds__(256) void ln_k(const float* __restrict__ x,
                                            const float* __restrict__ g,
                                            const float* __restrict__ b,
                                            bf16* __restrict__ out, int M){
  int row = blockIdx.x*4 + (threadIdx.x >> 6);
  int lane = threadIdx.x & 63;
  if (row >= M) return;
  const float* xr = x + (size_t)row*768;
  float4 v[3]; float s = 0.f;
  #pragma unroll
  for (int j=0;j<3;j++){
    v[j] = *(const float4*)(xr + lane*4 + j*256);
    s += v[j].x + v[j].y + v[j].z + v[j].w;
  }
  #pragma unroll
  for (int o=32;o;o>>=1) s += __shfl_xor(s, o);
  float mean = s * (1.f/768.f);
  float vs = 0.f;
  #pragma unroll
  for (int j=0;j<3;j++){
    float dx=v[j].x-mean, dy=v[j].y-mean, dz=v[j].z-mean, dw=v[j].w-mean;
    vs += dx*dx + dy*dy + dz*dz + dw*dw;
  }
  #pragma unroll
  for (int o=32;o;o>>=1) vs += __shfl_xor(vs, o);
  float rs = rsqrtf(vs*(1.f/768.f) + 1e-6f);
  bf16* orow = out + (size_t)row*768;
  #pragma unroll
  for (int j=0;j<3;j++){
    int d0 = lane*4 + j*256;
    float4 gv = *(const float4*)(g + d0);
    float4 bv = *(const float4*)(b + d0);
    uint2 pk;
    pk.x = pk2((v[j].x-mean)*rs*gv.x + bv.x, (v[j].y-mean)*rs*gv.y + bv.y);
    pk.y = pk2((v[j].z-mean)*rs*gv.z + bv.z, (v[j].w-mean)*rs*gv.w + bv.w);
    *(uint2*)(orow + d0) = pk;
  }
}

// ---------------- MFMA flash attention ----------------
__global__ __launch_bounds__(256) void attn_k(const bf16* __restrict__ qkv, bf16* __restrict__ o){
  __shared__ char Kc[2][32*128];
  __shared__ bf16 Vt[2][64][40];
  __shared__ bf16 Pl[4][32][40];

  const int blk = blockIdx.x;
  const int half = blk & 1, bh = blk >> 1;
  const int b = bh / 12, h = bh % 12;
  const int t = threadIdx.x, wave = t>>6, lane = t&63;
  const int qbase = half*128 + wave*32;
  const bf16* base = qkv + (size_t)b*NTOK*2304 + h*64;

  short8 qf[2][2];
  #pragma unroll
  for (int qt=0;qt<2;qt++){
    int row = qbase + qt*16 + (lane&15); row = row < NTOK ? row : NTOK-1;
    const bf16* qr = base + (size_t)row*2304 + (lane>>4)*8;
    qf[qt][0] = *(const short8*)(qr);
    qf[qt][1] = *(const short8*)(qr + 32);
  }

  f32x4 Oa[2][4];
  float mrow[2][4], srow[2][4];
  #pragma unroll
  for (int i=0;i<2;i++)
    #pragma unroll
    for (int j=0;j<4;j++){ Oa[i][j] = (f32x4){0.f,0.f,0.f,0.f}; }
  #pragma unroll
  for (int i=0;i<2;i++)
    #pragma unroll
    for (int j=0;j<4;j++){ mrow[i][j] = -1e30f; srow[i][j] = 0.f; }

  const int sr = t>>3, sc = (t&7)*8;
  auto ldK = [&](int c)->uint4{
    int kv = c*32 + sr; kv = kv < NTOK ? kv : NTOK-1;
    return *(const uint4*)(base + (size_t)kv*2304 + 768 + sc);
  };
  auto ldV = [&](int c)->uint4{
    int kv = c*32 + sr;
    uint4 r = {0,0,0,0};
    if (kv < NTOK) r = *(const uint4*)(base + (size_t)kv*2304 + 1536 + sc);
    return r;
  };
  auto wrK = [&](int buf, uint4 kvv){
    *(uint4*)(Kc[buf] + sr*128 + ((sc*2) ^ ((sr&7)<<4))) = kvv;
  };
  auto wrV = [&](int buf, uint4 vvv){
    union{ uint4 u; short s[8]; } w; w.u = vvv;
    #pragma unroll
    for (int j=0;j<8;j++) *(short*)&Vt[buf][sc+j][sr] = w.s[j];
  };

  { uint4 k0 = ldK(0), v0 = ldV(0); wrK(0,k0); wrV(0,v0); }
  __syncthreads();

  for (int c=0;c<7;c++){
    const int buf = c & 1;
    uint4 kn, vn; const bool pf = (c < 6);
    if (pf){ kn = ldK(c+1); vn = ldV(c+1); }

    f32x4 S[2][2];
    #pragma unroll
    for (int i=0;i<2;i++)
      #pragma unroll
      for (int j=0;j<2;j++) S[i][j] = (f32x4){0.f,0.f,0.f,0.f};
    #pragma unroll
    for (int kt=0;kt<2;kt++){
      int rk = kt*16 + (lane&15);
      const char* kb = Kc[buf] + rk*128;
      int swz = (rk&7)<<4;
      short8 b0 = *(const short8*)(kb + (((lane>>4)*16) ^ swz));
      short8 b1 = *(const short8*)(kb + ((64 + (lane>>4)*16) ^ swz));
      #pragma unroll
      for (int qt=0;qt<2;qt++){
        S[qt][kt] = __builtin_amdgcn_mfma_f32_16x16x32_bf16(qf[qt][0], b0, S[qt][kt],0,0,0);
        S[qt][kt] = __builtin_amdgcn_mfma_f32_16x16x32_bf16(qf[qt][1], b1, S[qt][kt],0,0,0);
      }
    }

    #pragma unroll
    for (int qt=0;qt<2;qt++){
      #pragma unroll
      for (int r=0;r<4;r++){
        float s0 = S[qt][0][r]*0.125f, s1 = S[qt][1][r]*0.125f;
        if (c == 6){
          if (192 + (lane&15) >= NTOK) s0 = -1e30f;
          s1 = -1e30f;
        }
        float mx = fmaxf(s0, s1);
        mx = fmaxf(mx, __shfl_xor(mx,1));
        mx = fmaxf(mx, __shfl_xor(mx,2));
        mx = fmaxf(mx, __shfl_xor(mx,4));
        mx = fmaxf(mx, __shfl_xor(mx,8));
        float mo = mrow[qt][r];
        float mn = fmaxf(mo, mx);
        float scl = __expf(mo - mn);
        mrow[qt][r] = mn;
        float p0 = __expf(s0 - mn), p1 = __expf(s1 - mn);
        srow[qt][r] = srow[qt][r]*scl + p0 + p1;
        #pragma unroll
        for (int dt=0;dt<4;dt++) Oa[qt][dt][r] *= scl;
        int pr = qt*16 + (lane>>4)*4 + r;
        Pl[wave][pr][lane&15]      = f2bf(p0);
        Pl[wave][pr][16+(lane&15)] = f2bf(p1);
      }
    }

    short8 vb[4];
    #pragma unroll
    for (int dt=0;dt<4;dt++)
      vb[dt] = *(const short8*)(&Vt[buf][dt*16+(lane&15)][(lane>>4)*8]);
    #pragma unroll
    for (int qt=0;qt<2;qt++){
      short8 pa = *(const short8*)(&Pl[wave][qt*16+(lane&15)][(lane>>4)*8]);
      #pragma unroll
      for (int dt=0;dt<4;dt++)
        Oa[qt][dt] = __builtin_amdgcn_mfma_f32_16x16x32_bf16(pa, vb[dt], Oa[qt][dt],0,0,0);
    }

    if (pf){ wrK(buf^1, kn); wrV(buf^1, vn); }
    __syncthreads();
  }

  #pragma unroll
  for (int qt=0;qt<2;qt++)
    #pragma unroll
    for (int r=0;r<4;r++){
      float s = srow[qt][r];
      s += __shfl_xor(s,1); s += __shfl_xor(s,2);
      s += __shfl_xor(s,4); s += __shfl_xor(s,8);
      srow[qt][r] = 1.f/s;
    }
  #pragma unroll
  for (int qt=0;qt<2;qt++){
    #pragma unroll
    for (int r=0;r<4;r++){
      int tok = qbase + qt*16 + (lane>>4)*4 + r;
      if (tok < NTOK){
        bf16* orow = o + ((size_t)(b*NTOK+tok))*768 + h*64 + (lane&15);
        float inv = srow[qt][r];
        #pragma unroll
        for (int dt=0;dt<4;dt++) orow[dt*16] = f2bf(Oa[qt][dt][r]*inv);
      }
    }
  }
}

// ---------------- mean-pool tokens 1..196 ----------------
__global__ void pool_k(const float* __restrict__ x, float* __restrict__ pooled){
  int idx = blockIdx.x*256 + threadIdx.x;
  if (idx >= 8*768) return;
  int b = idx / 768, d = idx % 768;
  float s = 0.f;
  for (int i=1;i<NTOK;i++) s += x[((size_t)(b*NTOK)+i)*768 + d];
  pooled[idx] = s * (1.f/196.f);
}

// ==================================================================
// Fused GEMM: C[M,N] = epi( A[M,K]bf16 @ dq(W)[N,K]^T + bias [+ lora] )
//   WTYPE 1: W nibble-packed (8 vals/uint32) + scales[N,Kst/64]
//   WTYPE 2: W fp32 * wscale
//   LORA 1: extra K=64 chunk: A = sum of 4 fp32 split-K partials of u,
//           W = 0.25 * Blora[N,64] fp32
//   OUTMODE 0: fp32 store (+kz*UROWS if KSPLIT>1); 1: bf16; 2: C += gvec[n]*v
//   ACT 0 none, 1 gelu, 2 relu
// Grid (KSPLIT==1): x = nt (fastest), y = mt; XCD-chunked bijective swizzle
// so consecutive blocks on one XCD share the A panel (mt) and W slab stays
// L2-resident. KSPLIT>1: x = mt, y = kz (nt=0).
// BM=64, BK=64, 4 waves 2x2, double-buffered LDS, reg-prefetch pipeline.
// ==================================================================
template<int BN, int WTYPE, int LORA, int OUTMODE, int ACT, int KSPLIT>
__global__ __launch_bounds__(256) void gemm_k(
    const bf16* __restrict__ A, const void* __restrict__ W,
    const float* __restrict__ scales, const float* __restrict__ upart,
    const float* __restrict__ Blora, const float* __restrict__ bias,
    const float* __restrict__ gvec, void* __restrict__ Cout,
    int M, int N, int Kst, int kiters, float wscale)
{
  constexpr int BM  = 64;
  constexpr int WCN = BN/2;
  constexpr int FM  = 2;
  constexpr int FN  = WCN/16;
  constexpr int EPT = BN/4;           // W elems per thread per k-iter
  constexpr int TPR = 64/EPT;
  constexpr int NLD = BN/16;          // uint4 loads for fp32 path
  constexpr int NPK = EPT/8;          // packed uint32 per thread (4 or 2)

  __shared__ char As[2][BM*128];
  __shared__ char Bs[2][BN*128];

  int mt, nt, kz;
  if (KSPLIT > 1){
    mt = blockIdx.x; nt = 0; kz = blockIdx.y;
  } else {
    int gx = gridDim.x;
    int nwg = gx * gridDim.y;
    int bid = blockIdx.y * gx + blockIdx.x;
    int q8 = nwg >> 3, r8 = nwg & 7, xcd = bid & 7, idx = bid >> 3;
    int swz = (xcd < r8 ? xcd*(q8+1) : r8*(q8+1) + (xcd-r8)*q8) + idx;
    mt = swz / gx; nt = swz - mt*gx; kz = 0;
  }
  const int k0 = kz * kiters;
  const int t = threadIdx.x, wave = t>>6, lane = t&63;
  const int wr = wave>>1, wc = wave&1;
  const int KT = kiters + (LORA ? 1 : 0);

  const int ar0 = t >> 3;
  const int acb = (t & 7) << 4;       // byte col in 128B row
  const int wrow = t / TPR;
  const int wko  = (t % TPR) * EPT;
  const int gnw  = nt*BN + wrow;

  f32x4 acc[FM][FN];
  #pragma unroll
  for (int i=0;i<FM;i++)
    #pragma unroll
    for (int j=0;j<FN;j++) acc[i][j] = (f32x4){0.f,0.f,0.f,0.f};

  auto loadA = [&](int it, uint4* av){
    #pragma unroll
    for (int i=0;i<2;i++){
      int gm = mt*BM + ar0 + 32*i; gm = gm < M ? gm : M-1;
      if (LORA && it == kiters){
        const float* up = upart + (size_t)gm*64 + (acb>>1);
        float a[8];
        #pragma unroll
        for (int k=0;k<8;k++) a[k] = 0.f;
        #pragma unroll
        for (int pz=0; pz<4; pz++){
          const float* q = up + (size_t)pz*UROWS;
          float4 x0 = *(const float4*)q;
          float4 x1 = *(const float4*)(q+4);
          a[0]+=x0.x; a[1]+=x0.y; a[2]+=x0.z; a[3]+=x0.w;
          a[4]+=x1.x; a[5]+=x1.y; a[6]+=x1.z; a[7]+=x1.w;
        }
        uint4 r; r.x=pk2(a[0],a[1]); r.y=pk2(a[2],a[3]);
        r.z=pk2(a[4],a[5]); r.w=pk2(a[6],a[7]);
        av[i] = r;
      } else {
        av[i] = *(const uint4*)((const char*)A + ((size_t)gm*Kst + (((size_t)(k0+it))<<6))*2 + acb);
      }
    }
  };
  auto writeA = [&](int buf, uint4* av){
    #pragma unroll
    for (int i=0;i<2;i++){
      int r = ar0 + 32*i;
      *(uint4*)(As[buf] + r*128 + (acb ^ ((r&7)<<4))) = av[i];
    }
  };
  // packed-nibble W path
  auto loadWp = [&](int it, uint4& pw, float& sc){
    const unsigned* qp = (const unsigned*)W + (size_t)gnw*(Kst>>3) + ((size_t)(k0+it)<<3) + (wko>>3);
    if (NPK == 4) pw = *(const uint4*)qp;
    else { uint2 v = *(const uint2*)qp; pw.x = v.x; pw.y = v.y; pw.z = 0; pw.w = 0; }
    sc = scales[(size_t)gnw*(Kst>>6) + k0 + it];
  };
  auto writeWp = [&](int buf, uint4 pw, float sc){
    #pragma unroll
    for (int c=0;c<NPK;c++){
      unsigned u = (&pw.x)[c];
      float f[8];
      #pragma unroll
      for (int j=0;j<8;j++) f[j] = ((float)((u >> (4*j)) & 15u) - 7.5f) * sc;
      uint4 val;
      val.x = pk2(f[0],f[1]); val.y = pk2(f[2],f[3]);
      val.z = pk2(f[4],f[5]); val.w = pk2(f[6],f[7]);
      int cb = (wko + c*8)*2;
      *(uint4*)(Bs[buf] + wrow*128 + (cb ^ ((wrow&7)<<4))) = val;
    }
  };
  // fp32 W path (WTYPE 2 and the LoRA K-chunk)
  auto loadWf = [&](int it, uint4* wv, float& sc){
    if (LORA && it == kiters){
      const float* fp = Blora + (size_t)gnw*64 + wko;
      #pragma unroll
      for (int c=0;c<NLD;c++) wv[c] = *(const uint4*)(fp + c*4);
      sc = 0.25f;
    } else {
      const float* fp = (const float*)W + (size_t)gnw*Kst + ((k0+it)<<6) + wko;
      #pragma unroll
      for (int c=0;c<NLD;c++) wv[c] = *(const uint4*)(fp + c*4);
      sc = wscale;
    }
  };
  auto writeWf = [&](int buf, uint4* wv, float sc){
    #pragma unroll
    for (int c=0;c<EPT/8;c++){
      unsigned pkv[4];
      #pragma unroll
      for (int j=0;j<4;j++){
        float f0 = __uint_as_float(((const unsigned*)wv)[c*8 + 2*j])*sc;
        float f1 = __uint_as_float(((const unsigned*)wv)[c*8 + 2*j + 1])*sc;
        pkv[j] = pk2(f0, f1);
      }
      int cb = (wko + c*8)*2;
      uint4 val; val.x=pkv[0]; val.y=pkv[1]; val.z=pkv[2]; val.w=pkv[3];
      *(uint4*)(Bs[buf] + wrow*128 + (cb ^ ((wrow&7)<<4))) = val;
    }
  };

  { // prologue: stage tile 0 into buf 0
    uint4 av[2]; loadA(0, av); writeA(0, av);
    if (WTYPE == 1){ uint4 pw; float sc; loadWp(0, pw, sc); writeWp(0, pw, sc); }
    else { uint4 wv[NLD]; float sc; loadWf(0, wv, sc); writeWf(0, wv, sc); }
  }
  __syncthreads();

  const int lrow = lane & 15;
  const int lkb  = (lane >> 4) * 16;

  for (int it=0; it<KT; ++it){
    const int buf = it & 1;
    uint4 av[2]; uint4 pw; uint4 wv[NLD]; float sc;
    const bool pf = (it+1 < KT);
    const bool nextPacked = (WTYPE == 1) && !(LORA && (it+1) == kiters);
    if (pf){
      loadA(it+1, av);
      if (nextPacked) loadWp(it+1, pw, sc);
      else            loadWf(it+1, wv, sc);
    }

    #pragma unroll
    for (int kk=0; kk<2; kk++){
      short8 af[FM]; short8 bw[FN];
      #pragma unroll
      for (int f=0; f<FM; f++){
        int ra = wr*32 + f*16 + lrow;
        af[f] = *(const short8*)(As[buf] + ra*128 + ((kk*64 + lkb) ^ ((ra&7)<<4)));
      }
      #pragma unroll
      for (int f=0; f<FN; f++){
        int rb = wc*WCN + f*16 + lrow;
        bw[f] = *(const short8*)(Bs[buf] + rb*128 + ((kk*64 + lkb) ^ ((rb&7)<<4)));
      }
      #pragma unroll
      for (int i=0;i<FM;i++)
        #pragma unroll
        for (int j=0;j<FN;j++)
          acc[i][j] = __builtin_amdgcn_mfma_f32_16x16x32_bf16(af[i], bw[j], acc[i][j], 0, 0, 0);
    }

    if (pf){
      writeA(buf^1, av);
      if (nextPacked) writeWp(buf^1, pw, sc);
      else            writeWf(buf^1, wv, sc);
    }
    __syncthreads();
  }

  // epilogue
  const int erow = (lane >> 4) * 4, ecol = lane & 15;
  #pragma unroll
  for (int i=0;i<FM;i++){
    #pragma unroll
    for (int j=0;j<FN;j++){
      int n = nt*BN + wc*WCN + j*16 + ecol;
      float bv = (bias != nullptr) ? bias[n] : 0.f;
      float gv = (OUTMODE==2) ? gvec[n] : 0.f;
      #pragma unroll
      for (int q=0; q<4; q++){
        int m = mt*BM + wr*32 + i*16 + erow + q;
        if (m < M){
          float v = acc[i][j][q] + bv;
          if (ACT == 1) v = gelu_tanh(v);
          if (ACT == 2) v = fmaxf(v, 0.f);
          size_t off = (size_t)m*N + n;
          if (OUTMODE == 0)      ((float*)Cout)[(size_t)kz*UROWS*(KSPLIT>1) + off] = v;
          else if (OUTMODE == 1) ((bf16*)Cout)[off] = f2bf(v);
          else                   ((float*)Cout)[off] += gv * v;
        }
      }
    }
  }
}

// ===================================================================
extern "C" void kernel_launch(void* const* d_in, const int* in_sizes, int n_in,
                              void* d_out, int out_size, void* d_ws, size_t ws_size,
                              hipStream_t stream){
  (void)in_sizes; (void)n_in; (void)out_size; (void)ws_size;
  const float* img    = (const float*)d_in[0];
  const float* patchw = (const float*)d_in[1];
  const float* patchb = (const float*)d_in[2];
  const float* cls    = (const float*)d_in[3];
  const float* ln1g   = (const float*)d_in[4];
  const float* ln1b   = (const float*)d_in[5];
  const float* ln2g   = (const float*)d_in[6];
  const float* ln2b   = (const float*)d_in[7];
  const float* g1     = (const float*)d_in[8];
  const float* g2     = (const float*)d_in[9];
  const int*   qkvq   = (const int*)d_in[10];
  const float* qkvs   = (const float*)d_in[11];
  const float* qkvb   = (const float*)d_in[12];
  const float* aQ     = (const float*)d_in[13];
  const float* bQ     = (const float*)d_in[14];
  const int*   projq  = (const int*)d_in[15];
  const float* projs  = (const float*)d_in[16];
  const float* projb  = (const float*)d_in[17];
  const float* aP     = (const float*)d_in[18];
  const float* bP     = (const float*)d_in[19];
  const int*   fc1q   = (const int*)d_in[20];
  const float* fc1s   = (const float*)d_in[21];
  const float* fc1b   = (const float*)d_in[22];
  const int*   fc2q   = (const int*)d_in[23];
  const float* fc2s   = (const float*)d_in[24];
  const float* fc2b   = (const float*)d_in[25];
  const float* fcn_g  = (const float*)d_in[26];
  const float* fcn_b  = (const float*)d_in[27];
  const float* headw  = (const float*)d_in[28];
  const float* headb  = (const float*)d_in[29];
  float* out = (float*)d_out;

  char* wp = (char*)d_ws;
  auto alloc = [&](size_t bytes)->char* {
    char* r = wp; wp += (bytes + 255) & ~(size_t)255; return r;
  };
  float* x      = (float*)alloc((size_t)MTOK*768*4);
  float* tmp    = (float*)alloc((size_t)MTOK*768*4);
  bf16*  qkvo   = (bf16*) alloc((size_t)MTOK*2304*2);
  bf16*  h      = (bf16*) alloc((size_t)MTOK*768*2);
  bf16*  h1     = (bf16*) alloc((size_t)MTOK*3072*2);
  bf16*  ob     = (bf16*) alloc((size_t)MTOK*768*2);
  float* u_part = (float*)alloc((size_t)4*UROWS*4);
  bf16*  p      = (bf16*) alloc((size_t)MPATCH*768*2);
  float* pooled = (float*)alloc((size_t)8*768*4);
  bf16*  pooledb= (bf16*) alloc((size_t)8*768*2);
  unsigned* pq_qkv = (unsigned*)alloc((size_t)12*2304*768/2);
  unsigned* pq_proj= (unsigned*)alloc((size_t)12*768*768/2);
  unsigned* pq_fc1 = (unsigned*)alloc((size_t)12*3072*768/2);
  unsigned* pq_fc2 = (unsigned*)alloc((size_t)12*768*3072/2);

  const int GM = (MTOK + 63) / 64;   // 25

  // one-time (per launch) weight repack: int32 -> nibble
  pack_k<<<2048, 256, 0, stream>>>(qkvq, pq_qkv, 12*2304*768/8);
  pack_k<<<2048, 256, 0, stream>>>(projq, pq_proj, 12*768*768/8);
  pack_k<<<2048, 256, 0, stream>>>(fc1q, pq_fc1, 12*3072*768/8);
  pack_k<<<2048, 256, 0, stream>>>(fc2q, pq_fc2, 12*768*3072/8);

  patchify_k<<<(MPATCH*768 + 255)/256, 256, 0, stream>>>(img, p);
  gemm_k<64,2,0,0,0,1><<<dim3(768/64, (MPATCH+63)/64), 256, 0, stream>>>(
      p, patchw, nullptr, nullptr, nullptr, patchb, nullptr, tmp,
      MPATCH, 768, 768, 12, 1.f);
  assemble_k<<<(MTOK*768 + 255)/256, 256, 0, stream>>>(tmp, cls, x);

  for (int l=0; l<12; l++){
    const unsigned* qkvp_l = pq_qkv + (size_t)l*2304*768/8;
    const float*    qkvs_l = qkvs + (size_t)l*2304*12;
    const unsigned* projp_l= pq_proj + (size_t)l*768*768/8;
    const float*    projs_l= projs + (size_t)l*768*12;
    const unsigned* fc1p_l = pq_fc1 + (size_t)l*3072*768/8;
    const float*    fc1s_l = fc1s + (size_t)l*3072*12;
    const unsigned* fc2p_l = pq_fc2 + (size_t)l*768*3072/8;
    const float*    fc2s_l = fc2s + (size_t)l*768*48;

    // h = LN1(x)
    ln_k<<<(MTOK+3)/4, 256, 0, stream>>>(x, ln1g + l*768, ln1b + l*768, h, MTOK);
    // u partials = h @ aQ^T (split-K x4)
    gemm_k<64,2,0,0,0,4><<<dim3(GM, 4), 256, 0, stream>>>(
        h, aQ + (size_t)l*64*768, nullptr, nullptr, nullptr, nullptr, nullptr, u_part,
        MTOK, 64, 768, 3, 1.f);
    // qkv = h @ dq(Wqkv)^T + qkv_b + 0.25*u@bQ^T  (bf16 out)
    gemm_k<128,1,1,1,0,1><<<dim3(2304/128, GM), 256, 0, stream>>>(
        h, qkvp_l, qkvs_l, u_part, bQ + (size_t)l*2304*64, qkvb + (size_t)l*2304,
        nullptr, qkvo, MTOK, 2304, 768, 12, 1.f);
    // attention -> ob (bf16)
    attn_k<<<192, 256, 0, stream>>>(qkvo, ob);
    // u partials = ob @ aP^T
    gemm_k<64,2,0,0,0,4><<<dim3(GM, 4), 256, 0, stream>>>(
        ob, aP + (size_t)l*64*768, nullptr, nullptr, nullptr, nullptr, nullptr, u_part,
        MTOK, 64, 768, 3, 1.f);
    // x += g1 * (ob @ dq(Wproj)^T + proj_b + 0.25*u@bP^T)
    gemm_k<64,1,1,2,0,1><<<dim3(768/64, GM), 256, 0, stream>>>(
        ob, projp_l, projs_l, u_part, bP + (size_t)l*768*64, projb + (size_t)l*768,
        g1 + l*768, x, MTOK, 768, 768, 12, 1.f);

    // h = LN2(x); h1 = gelu(h @ dq(Wfc1)^T + fc1_b)
    ln_k<<<(MTOK+3)/4, 256, 0, stream>>>(x, ln2g + l*768, ln2b + l*768, h, MTOK);
    gemm_k<128,1,0,1,1,1><<<dim3(3072/128, GM), 256, 0, stream>>>(
        h, fc1p_l, fc1s_l, nullptr, nullptr, fc1b + (size_t)l*3072,
        nullptr, h1, MTOK, 3072, 768, 12, 1.f);
    // x += g2 * (h1 @ dq(Wfc2)^T + fc2_b)
    gemm_k<64,1,0,2,0,1><<<dim3(768/64, GM), 256, 0, stream>>>(
        h1, fc2p_l, fc2s_l, nullptr, nullptr, fc2b + (size_t)l*768,
        g2 + l*768, x, MTOK, 768, 3072, 48, 1.f);
  }

  pool_k<<<(8*768 + 255)/256, 256, 0, stream>>>(x, pooled);
  ln_k<<<2, 256, 0, stream>>>(pooled, fcn_g, fcn_b, pooledb, 8);
  gemm_k<128,2,0,0,2,1><<<dim3(512/128, 1), 256, 0, stream>>>(
      pooledb, headw, nullptr, nullptr, nullptr, headb, nullptr, out,
      8, 512, 768, 12, 1.f);
}

// Round 5
// 2264.250 us; speedup vs baseline: 3.0440x; 1.0770x over previous
//
#include <hip/hip_runtime.h>
#include <hip/hip_bf16.h>

using bf16 = __hip_bfloat16;
typedef __attribute__((ext_vector_type(8))) short short8;
typedef __attribute__((ext_vector_type(4))) float f32x4;

#define NTOK 197
#define MTOK 1576   // 8*197
#define MPATCH 1568 // 8*196
#define UROWS 102400 // 1600*64, one split-K partial slab of u

static __device__ __forceinline__ float bf2f(bf16 v){ return __bfloat162float(v); }
static __device__ __forceinline__ bf16 f2bf(float v){ return __float2bfloat16(v); }
static __device__ __forceinline__ unsigned pk2(float a, float b){
  union{ bf16 h[2]; unsigned u; } r; r.h[0]=f2bf(a); r.h[1]=f2bf(b); return r.u;
}

static __device__ __forceinline__ float gelu_tanh(float x){
  float x3 = x*x*x;
  float a = 0.7978845608028654f*(x + 0.044715f*x3);
  float e = __expf(-2.f*fabsf(a));
  float t = (1.f-e)/(1.f+e);
  t = (a >= 0.f) ? t : -t;
  return 0.5f*x*(1.f+t);
}

// barrier WITHOUT vmcnt drain: LDS ops settled, global loads stay in flight (T4)
static __device__ __forceinline__ void lds_barrier(){
  asm volatile("s_waitcnt lgkmcnt(0)\n\ts_barrier" ::: "memory");
}

// ---------------- pack int4-in-int32 -> nibbles (8 vals per uint32) ----------------
__global__ void pack_k(const int* __restrict__ q, unsigned* __restrict__ o, int n8){
  for (int i = blockIdx.x*256 + threadIdx.x; i < n8; i += gridDim.x*256){
    int4 a = *(const int4*)(q + (size_t)i*8);
    int4 b = *(const int4*)(q + (size_t)i*8 + 4);
    unsigned r = (unsigned)a.x | ((unsigned)a.y<<4) | ((unsigned)a.z<<8) | ((unsigned)a.w<<12)
               | ((unsigned)b.x<<16) | ((unsigned)b.y<<20) | ((unsigned)b.z<<24) | ((unsigned)b.w<<28);
    o[i] = r;
  }
}

// ---------------- patchify ----------------
__global__ void patchify_k(const float* __restrict__ img, bf16* __restrict__ p){
  int idx = blockIdx.x*256 + threadIdx.x;
  if (idx >= MPATCH*768) return;
  int col = idx % 768, pr = idx / 768;
  int b = pr / 196, patch = pr % 196;
  int c = col >> 8, rem = col & 255, py = rem >> 4, px = rem & 15;
  int gy = patch / 14, gx = patch % 14;
  float v = img[(((size_t)(b*3 + c))*224 + gy*16 + py)*224 + gx*16 + px];
  p[idx] = f2bf(v);
}

// ---------------- assemble x = [cls ; tok] ----------------
__global__ void assemble_k(const float* __restrict__ tok, const float* __restrict__ cls,
                           float* __restrict__ x){
  int idx = blockIdx.x*256 + threadIdx.x;
  if (idx >= MTOK*768) return;
  int d = idx % 768, row = idx / 768;
  int b = row / NTOK, r = row % NTOK;
  x[idx] = (r == 0) ? cls[d] : tok[((size_t)(b*196) + r - 1)*768 + d];
}

// ---------------- LayerNorm ----------------
__global__ __launch_bounds__(256) void ln_k(const float* __restrict__ x,
                                            const float* __restrict__ g,
                                            const float* __restrict__ b,
                                            bf16* __restrict__ out, int M){
  int row = blockIdx.x*4 + (threadIdx.x >> 6);
  int lane = threadIdx.x & 63;
  if (row >= M) return;
  const float* xr = x + (size_t)row*768;
  float4 v[3]; float s = 0.f;
  #pragma unroll
  for (int j=0;j<3;j++){
    v[j] = *(const float4*)(xr + lane*4 + j*256);
    s += v[j].x + v[j].y + v[j].z + v[j].w;
  }
  #pragma unroll
  for (int o=32;o;o>>=1) s += __shfl_xor(s, o);
  float mean = s * (1.f/768.f);
  float vs = 0.f;
  #pragma unroll
  for (int j=0;j<3;j++){
    float dx=v[j].x-mean, dy=v[j].y-mean, dz=v[j].z-mean, dw=v[j].w-mean;
    vs += dx*dx + dy*dy + dz*dz + dw*dw;
  }
  #pragma unroll
  for (int o=32;o;o>>=1) vs += __shfl_xor(vs, o);
  float rs = rsqrtf(vs*(1.f/768.f) + 1e-6f);
  bf16* orow = out + (size_t)row*768;
  #pragma unroll
  for (int j=0;j<3;j++){
    int d0 = lane*4 + j*256;
    float4 gv = *(const float4*)(g + d0);
    float4 bv = *(const float4*)(b + d0);
    uint2 pk;
    pk.x = pk2((v[j].x-mean)*rs*gv.x + bv.x, (v[j].y-mean)*rs*gv.y + bv.y);
    pk.y = pk2((v[j].z-mean)*rs*gv.z + bv.z, (v[j].w-mean)*rs*gv.w + bv.w);
    *(uint2*)(orow + d0) = pk;
  }
}

// ---------------- MFMA flash attention ----------------
__global__ __launch_bounds__(256) void attn_k(const bf16* __restrict__ qkv, bf16* __restrict__ o){
  __shared__ char Kc[2][32*128];
  __shared__ bf16 Vt[2][64][40];
  __shared__ bf16 Pl[4][32][40];

  const int blk = blockIdx.x;
  const int half = blk & 1, bh = blk >> 1;
  const int b = bh / 12, h = bh % 12;
  const int t = threadIdx.x, wave = t>>6, lane = t&63;
  const int qbase = half*128 + wave*32;
  const bf16* base = qkv + (size_t)b*NTOK*2304 + h*64;

  short8 qf[2][2];
  #pragma unroll
  for (int qt=0;qt<2;qt++){
    int row = qbase + qt*16 + (lane&15); row = row < NTOK ? row : NTOK-1;
    const bf16* qr = base + (size_t)row*2304 + (lane>>4)*8;
    qf[qt][0] = *(const short8*)(qr);
    qf[qt][1] = *(const short8*)(qr + 32);
  }

  f32x4 Oa[2][4];
  float mrow[2][4], srow[2][4];
  #pragma unroll
  for (int i=0;i<2;i++)
    #pragma unroll
    for (int j=0;j<4;j++){ Oa[i][j] = (f32x4){0.f,0.f,0.f,0.f}; }
  #pragma unroll
  for (int i=0;i<2;i++)
    #pragma unroll
    for (int j=0;j<4;j++){ mrow[i][j] = -1e30f; srow[i][j] = 0.f; }

  const int sr = t>>3, sc = (t&7)*8;
  auto ldK = [&](int c)->uint4{
    int kv = c*32 + sr; kv = kv < NTOK ? kv : NTOK-1;
    return *(const uint4*)(base + (size_t)kv*2304 + 768 + sc);
  };
  auto ldV = [&](int c)->uint4{
    int kv = c*32 + sr;
    uint4 r = {0,0,0,0};
    if (kv < NTOK) r = *(const uint4*)(base + (size_t)kv*2304 + 1536 + sc);
    return r;
  };
  auto wrK = [&](int buf, uint4 kvv){
    *(uint4*)(Kc[buf] + sr*128 + ((sc*2) ^ ((sr&7)<<4))) = kvv;
  };
  auto wrV = [&](int buf, uint4 vvv){
    union{ uint4 u; short s[8]; } w; w.u = vvv;
    #pragma unroll
    for (int j=0;j<8;j++) *(short*)&Vt[buf][sc+j][sr] = w.s[j];
  };

  { uint4 k0 = ldK(0), v0 = ldV(0); wrK(0,k0); wrV(0,v0); }
  __syncthreads();

  for (int c=0;c<7;c++){
    const int buf = c & 1;
    uint4 kn, vn; const bool pf = (c < 6);
    if (pf){ kn = ldK(c+1); vn = ldV(c+1); }

    f32x4 S[2][2];
    #pragma unroll
    for (int i=0;i<2;i++)
      #pragma unroll
      for (int j=0;j<2;j++) S[i][j] = (f32x4){0.f,0.f,0.f,0.f};
    #pragma unroll
    for (int kt=0;kt<2;kt++){
      int rk = kt*16 + (lane&15);
      const char* kb = Kc[buf] + rk*128;
      int swz = (rk&7)<<4;
      short8 b0 = *(const short8*)(kb + (((lane>>4)*16) ^ swz));
      short8 b1 = *(const short8*)(kb + ((64 + (lane>>4)*16) ^ swz));
      #pragma unroll
      for (int qt=0;qt<2;qt++){
        S[qt][kt] = __builtin_amdgcn_mfma_f32_16x16x32_bf16(qf[qt][0], b0, S[qt][kt],0,0,0);
        S[qt][kt] = __builtin_amdgcn_mfma_f32_16x16x32_bf16(qf[qt][1], b1, S[qt][kt],0,0,0);
      }
    }

    #pragma unroll
    for (int qt=0;qt<2;qt++){
      #pragma unroll
      for (int r=0;r<4;r++){
        float s0 = S[qt][0][r]*0.125f, s1 = S[qt][1][r]*0.125f;
        if (c == 6){
          if (192 + (lane&15) >= NTOK) s0 = -1e30f;
          s1 = -1e30f;
        }
        float mx = fmaxf(s0, s1);
        mx = fmaxf(mx, __shfl_xor(mx,1));
        mx = fmaxf(mx, __shfl_xor(mx,2));
        mx = fmaxf(mx, __shfl_xor(mx,4));
        mx = fmaxf(mx, __shfl_xor(mx,8));
        float mo = mrow[qt][r];
        float mn = fmaxf(mo, mx);
        float scl = __expf(mo - mn);
        mrow[qt][r] = mn;
        float p0 = __expf(s0 - mn), p1 = __expf(s1 - mn);
        srow[qt][r] = srow[qt][r]*scl + p0 + p1;
        #pragma unroll
        for (int dt=0;dt<4;dt++) Oa[qt][dt][r] *= scl;
        int pr = qt*16 + (lane>>4)*4 + r;
        Pl[wave][pr][lane&15]      = f2bf(p0);
        Pl[wave][pr][16+(lane&15)] = f2bf(p1);
      }
    }

    short8 vb[4];
    #pragma unroll
    for (int dt=0;dt<4;dt++)
      vb[dt] = *(const short8*)(&Vt[buf][dt*16+(lane&15)][(lane>>4)*8]);
    #pragma unroll
    for (int qt=0;qt<2;qt++){
      short8 pa = *(const short8*)(&Pl[wave][qt*16+(lane&15)][(lane>>4)*8]);
      #pragma unroll
      for (int dt=0;dt<4;dt++)
        Oa[qt][dt] = __builtin_amdgcn_mfma_f32_16x16x32_bf16(pa, vb[dt], Oa[qt][dt],0,0,0);
    }

    if (pf){ wrK(buf^1, kn); wrV(buf^1, vn); }
    __syncthreads();
  }

  #pragma unroll
  for (int qt=0;qt<2;qt++)
    #pragma unroll
    for (int r=0;r<4;r++){
      float s = srow[qt][r];
      s += __shfl_xor(s,1); s += __shfl_xor(s,2);
      s += __shfl_xor(s,4); s += __shfl_xor(s,8);
      srow[qt][r] = 1.f/s;
    }
  #pragma unroll
  for (int qt=0;qt<2;qt++){
    #pragma unroll
    for (int r=0;r<4;r++){
      int tok = qbase + qt*16 + (lane>>4)*4 + r;
      if (tok < NTOK){
        bf16* orow = o + ((size_t)(b*NTOK+tok))*768 + h*64 + (lane&15);
        float inv = srow[qt][r];
        #pragma unroll
        for (int dt=0;dt<4;dt++) orow[dt*16] = f2bf(Oa[qt][dt][r]*inv);
      }
    }
  }
}

// ---------------- mean-pool ----------------
__global__ void pool_k(const float* __restrict__ x, float* __restrict__ pooled){
  int idx = blockIdx.x*256 + threadIdx.x;
  if (idx >= 8*768) return;
  int b = idx / 768, d = idx % 768;
  float s = 0.f;
  for (int i=1;i<NTOK;i++) s += x[((size_t)(b*NTOK)+i)*768 + d];
  pooled[idx] = s * (1.f/196.f);
}

// ---------------- fc2 split-K reduce + bias + gamma-residual ----------------
__global__ void redres_k(const float* __restrict__ part, const float* __restrict__ bias,
                         const float* __restrict__ g, float* __restrict__ x){
  int i = blockIdx.x*256 + threadIdx.x;
  if (i >= (MTOK*768)/4) return;
  int d = (i*4) % 768;
  float4 p0 = *(const float4*)(part + (size_t)i*4);
  float4 p1 = *(const float4*)(part + (size_t)MTOK*768 + (size_t)i*4);
  float4 bv = *(const float4*)(bias + d);
  float4 gv = *(const float4*)(g + d);
  float4 xv = *(float4*)(x + (size_t)i*4);
  xv.x += gv.x*(p0.x+p1.x+bv.x);
  xv.y += gv.y*(p0.y+p1.y+bv.y);
  xv.z += gv.z*(p0.z+p1.z+bv.z);
  xv.w += gv.w*(p0.w+p1.w+bv.w);
  *(float4*)(x + (size_t)i*4) = xv;
}

// ==================================================================
// Fused GEMM with 2-deep register pipeline + counted-vmcnt raw barriers.
//   WTYPE 1: W nibble-packed + scales[N,Kst/64]; WTYPE 2: W fp32 * wscale
//   LORA 1: extra K=64 chunk (A = sum of 4 u-partials, W = 0.25*Blora fp32)
//   OUTMODE 0: fp32 store at Cout + kz*kslab; 1: bf16; 2: C += gvec[n]*v
//   ACT 0 none, 1 gelu, 2 relu.  kz = blockIdx.z; k0 = kz*kiters.
// ==================================================================
template<int BN, int WTYPE, int LORA, int OUTMODE, int ACT>
__global__ __launch_bounds__(256) void gemm_k(
    const bf16* __restrict__ A, const void* __restrict__ W,
    const float* __restrict__ scales, const float* __restrict__ upart,
    const float* __restrict__ Blora, const float* __restrict__ bias,
    const float* __restrict__ gvec, void* __restrict__ Cout,
    int M, int N, int Kst, int kiters, size_t kslab, float wscale)
{
  constexpr int BM  = 64;
  constexpr int WCN = BN/2;
  constexpr int FM  = 2;
  constexpr int FN  = WCN/16;
  constexpr int EPT = BN/4;
  constexpr int TPR = 64/EPT;
  constexpr int NLD = BN/16;
  constexpr int NPK = EPT/8;

  __shared__ char As[2][BM*128];
  __shared__ char Bs[2][BN*128];

  int mt, nt;
  {
    int gx = gridDim.x;
    int nwg = gx * gridDim.y;
    int bid = blockIdx.y * gx + blockIdx.x;
    int q8 = nwg >> 3, r8 = nwg & 7, xcd = bid & 7, idx = bid >> 3;
    int swz = (xcd < r8 ? xcd*(q8+1) : r8*(q8+1) + (xcd-r8)*q8) + idx;
    mt = swz / gx; nt = swz - mt*gx;
  }
  const int kz = blockIdx.z;
  const int k0 = kz * kiters;
  const int t = threadIdx.x, wave = t>>6, lane = t&63;
  const int wr = wave>>1, wc = wave&1;
  const int KT = kiters + (LORA ? 1 : 0);

  const int ar0 = t >> 3;
  const int acb = (t & 7) << 4;
  const int wrow = t / TPR;
  const int wko  = (t % TPR) * EPT;
  const int gnw  = nt*BN + wrow;

  f32x4 acc[FM][FN];
  #pragma unroll
  for (int i=0;i<FM;i++)
    #pragma unroll
    for (int j=0;j<FN;j++) acc[i][j] = (f32x4){0.f,0.f,0.f,0.f};

  auto loadA = [&](int it, uint4* av){
    #pragma unroll
    for (int i=0;i<2;i++){
      int gm = mt*BM + ar0 + 32*i; gm = gm < M ? gm : M-1;
      if (LORA && it == kiters){
        const float* up = upart + (size_t)gm*64 + (acb>>1);
        float a[8];
        #pragma unroll
        for (int k=0;k<8;k++) a[k] = 0.f;
        #pragma unroll
        for (int pz=0; pz<4; pz++){
          const float* q = up + (size_t)pz*UROWS;
          float4 x0 = *(const float4*)q;
          float4 x1 = *(const float4*)(q+4);
          a[0]+=x0.x; a[1]+=x0.y; a[2]+=x0.z; a[3]+=x0.w;
          a[4]+=x1.x; a[5]+=x1.y; a[6]+=x1.z; a[7]+=x1.w;
        }
        uint4 r; r.x=pk2(a[0],a[1]); r.y=pk2(a[2],a[3]);
        r.z=pk2(a[4],a[5]); r.w=pk2(a[6],a[7]);
        av[i] = r;
      } else {
        av[i] = *(const uint4*)((const char*)A + ((size_t)gm*Kst + (((size_t)(k0+it))<<6))*2 + acb);
      }
    }
  };
  auto writeA = [&](int buf, uint4* av){
    #pragma unroll
    for (int i=0;i<2;i++){
      int r = ar0 + 32*i;
      *(uint4*)(As[buf] + r*128 + (acb ^ ((r&7)<<4))) = av[i];
    }
  };
  auto loadWp = [&](int it, uint4& pw, float& sc){
    const unsigned* qp = (const unsigned*)W + (size_t)gnw*(Kst>>3) + ((size_t)(k0+it)<<3) + (wko>>3);
    if (NPK == 4) pw = *(const uint4*)qp;
    else { uint2 v = *(const uint2*)qp; pw.x = v.x; pw.y = v.y; pw.z = 0; pw.w = 0; }
    sc = scales[(size_t)gnw*(Kst>>6) + k0 + it];
  };
  auto writeWp = [&](int buf, uint4 pw, float sc){
    #pragma unroll
    for (int c=0;c<NPK;c++){
      unsigned u = (&pw.x)[c];
      float f[8];
      #pragma unroll
      for (int j=0;j<8;j++) f[j] = ((float)((u >> (4*j)) & 15u) - 7.5f) * sc;
      uint4 val;
      val.x = pk2(f[0],f[1]); val.y = pk2(f[2],f[3]);
      val.z = pk2(f[4],f[5]); val.w = pk2(f[6],f[7]);
      int cb = (wko + c*8)*2;
      *(uint4*)(Bs[buf] + wrow*128 + (cb ^ ((wrow&7)<<4))) = val;
    }
  };
  auto loadWf = [&](int it, uint4* wv, float& sc){
    if (LORA && it == kiters){
      const float* fp = Blora + (size_t)gnw*64 + wko;
      #pragma unroll
      for (int c=0;c<NLD;c++) wv[c] = *(const uint4*)(fp + c*4);
      sc = 0.25f;
    } else {
      const float* fp = (const float*)W + (size_t)gnw*Kst + ((k0+it)<<6) + wko;
      #pragma unroll
      for (int c=0;c<NLD;c++) wv[c] = *(const uint4*)(fp + c*4);
      sc = wscale;
    }
  };
  auto writeWf = [&](int buf, uint4* wv, float sc){
    #pragma unroll
    for (int c=0;c<EPT/8;c++){
      unsigned pkv[4];
      #pragma unroll
      for (int j=0;j<4;j++){
        float f0 = __uint_as_float(((const unsigned*)wv)[c*8 + 2*j])*sc;
        float f1 = __uint_as_float(((const unsigned*)wv)[c*8 + 2*j + 1])*sc;
        pkv[j] = pk2(f0, f1);
      }
      int cb = (wko + c*8)*2;
      uint4 val; val.x=pkv[0]; val.y=pkv[1]; val.z=pkv[2]; val.w=pkv[3];
      *(uint4*)(Bs[buf] + wrow*128 + (cb ^ ((wrow&7)<<4))) = val;
    }
  };

  auto loadS = [&](int it, uint4* av, uint4& pw, uint4* wv, float& sc){
    loadA(it, av);
    const bool packed = (WTYPE==1) && !(LORA && it==kiters);
    if (packed) loadWp(it, pw, sc);
    else        loadWf(it, wv, sc);
  };
  auto writeS = [&](int it, int buf, uint4* av, uint4& pw, uint4* wv, float sc){
    writeA(buf, av);
    const bool packed = (WTYPE==1) && !(LORA && it==kiters);
    if (packed) writeWp(buf, pw, sc);
    else        writeWf(buf, wv, sc);
  };

  const int lrow = lane & 15;
  const int lkb  = (lane >> 4) * 16;
  auto computeTile = [&](int buf){
    #pragma unroll
    for (int kk=0; kk<2; kk++){
      short8 af[FM]; short8 bw[FN];
      #pragma unroll
      for (int f=0; f<FM; f++){
        int ra = wr*32 + f*16 + lrow;
        af[f] = *(const short8*)(As[buf] + ra*128 + ((kk*64 + lkb) ^ ((ra&7)<<4)));
      }
      #pragma unroll
      for (int f=0; f<FN; f++){
        int rb = wc*WCN + f*16 + lrow;
        bw[f] = *(const short8*)(Bs[buf] + rb*128 + ((kk*64 + lkb) ^ ((rb&7)<<4)));
      }
      #pragma unroll
      for (int i=0;i<FM;i++)
        #pragma unroll
        for (int j=0;j<FN;j++)
          acc[i][j] = __builtin_amdgcn_mfma_f32_16x16x32_bf16(af[i], bw[j], acc[i][j], 0, 0, 0);
    }
  };

  // ---- 2-deep pipeline: sets SA/SB, loads stay in flight across raw barriers ----
  uint4 avA[2], avB[2], wvA[NLD], wvB[NLD];
  uint4 pwA, pwB; float scA, scB;

  loadS(0, avA, pwA, wvA, scA);
  writeS(0, 0, avA, pwA, wvA, scA);
  if (KT > 1) loadS(1, avB, pwB, wvB, scB);
  lds_barrier();

  int it = 0;
  while (true){
    if (it+2 < KT) loadS(it+2, avA, pwA, wvA, scA);
    computeTile(it & 1);
    if (it+1 < KT) writeS(it+1, (it+1)&1, avB, pwB, wvB, scB);
    lds_barrier();
    ++it; if (it >= KT) break;

    if (it+2 < KT) loadS(it+2, avB, pwB, wvB, scB);
    computeTile(it & 1);
    if (it+1 < KT) writeS(it+1, (it+1)&1, avA, pwA, wvA, scA);
    lds_barrier();
    ++it; if (it >= KT) break;
  }

  // epilogue
  const int erow = (lane >> 4) * 4, ecol = lane & 15;
  #pragma unroll
  for (int i=0;i<FM;i++){
    #pragma unroll
    for (int j=0;j<FN;j++){
      int n = nt*BN + wc*WCN + j*16 + ecol;
      float bv = (bias != nullptr) ? bias[n] : 0.f;
      float gv = (OUTMODE==2) ? gvec[n] : 0.f;
      #pragma unroll
      for (int q=0; q<4; q++){
        int m = mt*BM + wr*32 + i*16 + erow + q;
        if (m < M){
          float v = acc[i][j][q] + bv;
          if (ACT == 1) v = gelu_tanh(v);
          if (ACT == 2) v = fmaxf(v, 0.f);
          size_t off = (size_t)m*N + n;
          if (OUTMODE == 0)      ((float*)Cout)[(size_t)kz*kslab + off] = v;
          else if (OUTMODE == 1) ((bf16*)Cout)[off] = f2bf(v);
          else                   ((float*)Cout)[off] += gv * v;
        }
      }
    }
  }
}

// ===================================================================
extern "C" void kernel_launch(void* const* d_in, const int* in_sizes, int n_in,
                              void* d_out, int out_size, void* d_ws, size_t ws_size,
                              hipStream_t stream){
  (void)in_sizes; (void)n_in; (void)out_size; (void)ws_size;
  const float* img    = (const float*)d_in[0];
  const float* patchw = (const float*)d_in[1];
  const float* patchb = (const float*)d_in[2];
  const float* cls    = (const float*)d_in[3];
  const float* ln1g   = (const float*)d_in[4];
  const float* ln1b   = (const float*)d_in[5];
  const float* ln2g   = (const float*)d_in[6];
  const float* ln2b   = (const float*)d_in[7];
  const float* g1     = (const float*)d_in[8];
  const float* g2     = (const float*)d_in[9];
  const int*   qkvq   = (const int*)d_in[10];
  const float* qkvs   = (const float*)d_in[11];
  const float* qkvb   = (const float*)d_in[12];
  const float* aQ     = (const float*)d_in[13];
  const float* bQ     = (const float*)d_in[14];
  const int*   projq  = (const int*)d_in[15];
  const float* projs  = (const float*)d_in[16];
  const float* projb  = (const float*)d_in[17];
  const float* aP     = (const float*)d_in[18];
  const float* bP     = (const float*)d_in[19];
  const int*   fc1q   = (const int*)d_in[20];
  const float* fc1s   = (const float*)d_in[21];
  const float* fc1b   = (const float*)d_in[22];
  const int*   fc2q   = (const int*)d_in[23];
  const float* fc2s   = (const float*)d_in[24];
  const float* fc2b   = (const float*)d_in[25];
  const float* fcn_g  = (const float*)d_in[26];
  const float* fcn_b  = (const float*)d_in[27];
  const float* headw  = (const float*)d_in[28];
  const float* headb  = (const float*)d_in[29];
  float* out = (float*)d_out;

  char* wp = (char*)d_ws;
  auto alloc = [&](size_t bytes)->char* {
    char* r = wp; wp += (bytes + 255) & ~(size_t)255; return r;
  };
  float* x      = (float*)alloc((size_t)MTOK*768*4);
  float* fc2p   = (float*)alloc((size_t)2*MTOK*768*4);
  bf16*  qkvo   = (bf16*) alloc((size_t)MTOK*2304*2);
  bf16*  h      = (bf16*) alloc((size_t)MTOK*768*2);
  bf16*  h1     = (bf16*) alloc((size_t)MTOK*3072*2);
  bf16*  ob     = (bf16*) alloc((size_t)MTOK*768*2);
  float* u_part = (float*)alloc((size_t)4*UROWS*4);
  bf16*  p      = (bf16*) alloc((size_t)MPATCH*768*2);
  float* tmp    = (float*)alloc((size_t)MTOK*768*4);
  float* pooled = (float*)alloc((size_t)8*768*4);
  bf16*  pooledb= (bf16*) alloc((size_t)8*768*2);
  unsigned* pq_qkv = (unsigned*)alloc((size_t)12*2304*768/2);
  unsigned* pq_proj= (unsigned*)alloc((size_t)12*768*768/2);
  unsigned* pq_fc1 = (unsigned*)alloc((size_t)12*3072*768/2);
  unsigned* pq_fc2 = (unsigned*)alloc((size_t)12*768*3072/2);

  const int GM = (MTOK + 63) / 64;   // 25

  pack_k<<<2048, 256, 0, stream>>>(qkvq, pq_qkv, 12*2304*768/8);
  pack_k<<<2048, 256, 0, stream>>>(projq, pq_proj, 12*768*768/8);
  pack_k<<<2048, 256, 0, stream>>>(fc1q, pq_fc1, 12*3072*768/8);
  pack_k<<<2048, 256, 0, stream>>>(fc2q, pq_fc2, 12*768*3072/8);

  patchify_k<<<(MPATCH*768 + 255)/256, 256, 0, stream>>>(img, p);
  gemm_k<64,2,0,0,0><<<dim3(768/64, (MPATCH+63)/64, 1), 256, 0, stream>>>(
      p, patchw, nullptr, nullptr, nullptr, patchb, nullptr, tmp,
      MPATCH, 768, 768, 12, 0, 1.f);
  assemble_k<<<(MTOK*768 + 255)/256, 256, 0, stream>>>(tmp, cls, x);

  for (int l=0; l<12; l++){
    const unsigned* qkvp_l = pq_qkv + (size_t)l*2304*768/8;
    const float*    qkvs_l = qkvs + (size_t)l*2304*12;
    const unsigned* projp_l= pq_proj + (size_t)l*768*768/8;
    const float*    projs_l= projs + (size_t)l*768*12;
    const unsigned* fc1p_l = pq_fc1 + (size_t)l*3072*768/8;
    const float*    fc1s_l = fc1s + (size_t)l*3072*12;
    const unsigned* fc2p_l = pq_fc2 + (size_t)l*768*3072/8;
    const float*    fc2s_l = fc2s + (size_t)l*768*48;

    // h = LN1(x)
    ln_k<<<(MTOK+3)/4, 256, 0, stream>>>(x, ln1g + l*768, ln1b + l*768, h, MTOK);
    // u partials = h @ aQ^T (split-K x4 via blockIdx.z)
    gemm_k<64,2,0,0,0><<<dim3(1, GM, 4), 256, 0, stream>>>(
        h, aQ + (size_t)l*64*768, nullptr, nullptr, nullptr, nullptr, nullptr, u_part,
        MTOK, 64, 768, 3, UROWS, 1.f);
    // qkv = h @ dq(Wqkv)^T + qkv_b + 0.25*u@bQ^T  (bf16 out)
    gemm_k<128,1,1,1,0><<<dim3(2304/128, GM, 1), 256, 0, stream>>>(
        h, qkvp_l, qkvs_l, u_part, bQ + (size_t)l*2304*64, qkvb + (size_t)l*2304,
        nullptr, qkvo, MTOK, 2304, 768, 12, 0, 1.f);
    // attention -> ob (bf16)
    attn_k<<<192, 256, 0, stream>>>(qkvo, ob);
    // u partials = ob @ aP^T
    gemm_k<64,2,0,0,0><<<dim3(1, GM, 4), 256, 0, stream>>>(
        ob, aP + (size_t)l*64*768, nullptr, nullptr, nullptr, nullptr, nullptr, u_part,
        MTOK, 64, 768, 3, UROWS, 1.f);
    // x += g1 * (ob @ dq(Wproj)^T + proj_b + 0.25*u@bP^T)
    gemm_k<64,1,1,2,0><<<dim3(768/64, GM, 1), 256, 0, stream>>>(
        ob, projp_l, projs_l, u_part, bP + (size_t)l*768*64, projb + (size_t)l*768,
        g1 + l*768, x, MTOK, 768, 768, 12, 0, 1.f);

    // h = LN2(x); h1 = gelu(h @ dq(Wfc1)^T + fc1_b)
    ln_k<<<(MTOK+3)/4, 256, 0, stream>>>(x, ln2g + l*768, ln2b + l*768, h, MTOK);
    gemm_k<128,1,0,1,1><<<dim3(3072/128, GM, 1), 256, 0, stream>>>(
        h, fc1p_l, fc1s_l, nullptr, nullptr, fc1b + (size_t)l*3072,
        nullptr, h1, MTOK, 3072, 768, 12, 0, 1.f);
    // fc2 split-K x2 -> partials, then reduce + bias + g2-residual
    gemm_k<64,1,0,0,0><<<dim3(768/64, GM, 2), 256, 0, stream>>>(
        h1, fc2p_l, fc2s_l, nullptr, nullptr, nullptr,
        nullptr, fc2p, MTOK, 768, 3072, 24, (size_t)MTOK*768, 1.f);
    redres_k<<<((MTOK*768/4)+255)/256, 256, 0, stream>>>(
        fc2p, fc2b + (size_t)l*768, g2 + l*768, x);
  }

  pool_k<<<(8*768 + 255)/256, 256, 0, stream>>>(x, pooled);
  ln_k<<<2, 256, 0, stream>>>(pooled, fcn_g, fcn_b, pooledb, 8);
  gemm_k<128,2,0,0,2><<<dim3(512/128, 1, 1), 256, 0, stream>>>(
      pooledb, headw, nullptr, nullptr, nullptr, headb, nullptr, out,
      8, 512, 768, 12, 0, 1.f);
}

// Round 6
// 2133.276 us; speedup vs baseline: 3.2309x; 1.0614x over previous
//
#include <hip/hip_runtime.h>
#include <hip/hip_bf16.h>

using bf16 = __hip_bfloat16;
typedef __attribute__((ext_vector_type(8))) short short8;
typedef __attribute__((ext_vector_type(4))) float f32x4;

#define NTOK 197
#define MTOK 1576   // 8*197
#define MPATCH 1568 // 8*196
#define UROWS 102400 // 1600*64, one split-K partial slab of u

static __device__ __forceinline__ float bf2f(bf16 v){ return __bfloat162float(v); }
static __device__ __forceinline__ bf16 f2bf(float v){ return __float2bfloat16(v); }
static __device__ __forceinline__ unsigned pk2(float a, float b){
  union{ bf16 h[2]; unsigned u; } r; r.h[0]=f2bf(a); r.h[1]=f2bf(b); return r.u;
}

static __device__ __forceinline__ float gelu_tanh(float x){
  float x3 = x*x*x;
  float a = 0.7978845608028654f*(x + 0.044715f*x3);
  float e = __expf(-2.f*fabsf(a));
  float t = (1.f-e)/(1.f+e);
  t = (a >= 0.f) ? t : -t;
  return 0.5f*x*(1.f+t);
}

// barrier WITHOUT vmcnt drain: LDS ops settled, global loads stay in flight (T4)
static __device__ __forceinline__ void lds_barrier(){
  asm volatile("s_waitcnt lgkmcnt(0)\n\ts_barrier" ::: "memory");
}

// ---------------- pack int4-in-int32 -> nibbles (8 vals per uint32) ----------------
__global__ void pack_k(const int* __restrict__ q, unsigned* __restrict__ o, int n8){
  for (int i = blockIdx.x*256 + threadIdx.x; i < n8; i += gridDim.x*256){
    int4 a = *(const int4*)(q + (size_t)i*8);
    int4 b = *(const int4*)(q + (size_t)i*8 + 4);
    unsigned r = (unsigned)a.x | ((unsigned)a.y<<4) | ((unsigned)a.z<<8) | ((unsigned)a.w<<12)
               | ((unsigned)b.x<<16) | ((unsigned)b.y<<20) | ((unsigned)b.z<<24) | ((unsigned)b.w<<28);
    o[i] = r;
  }
}

// ---------------- patchify ----------------
__global__ void patchify_k(const float* __restrict__ img, bf16* __restrict__ p){
  int idx = blockIdx.x*256 + threadIdx.x;
  if (idx >= MPATCH*768) return;
  int col = idx % 768, pr = idx / 768;
  int b = pr / 196, patch = pr % 196;
  int c = col >> 8, rem = col & 255, py = rem >> 4, px = rem & 15;
  int gy = patch / 14, gx = patch % 14;
  float v = img[(((size_t)(b*3 + c))*224 + gy*16 + py)*224 + gx*16 + px];
  p[idx] = f2bf(v);
}

// ---------------- assemble x = [cls ; tok] ----------------
__global__ void assemble_k(const float* __restrict__ tok, const float* __restrict__ cls,
                           float* __restrict__ x){
  int idx = blockIdx.x*256 + threadIdx.x;
  if (idx >= MTOK*768) return;
  int d = idx % 768, row = idx / 768;
  int b = row / NTOK, r = row % NTOK;
  x[idx] = (r == 0) ? cls[d] : tok[((size_t)(b*196) + r - 1)*768 + d];
}

// ---------------- LayerNorm ----------------
__global__ __launch_bounds__(256) void ln_k(const float* __restrict__ x,
                                            const float* __restrict__ g,
                                            const float* __restrict__ b,
                                            bf16* __restrict__ out, int M){
  int row = blockIdx.x*4 + (threadIdx.x >> 6);
  int lane = threadIdx.x & 63;
  if (row >= M) return;
  const float* xr = x + (size_t)row*768;
  float4 v[3]; float s = 0.f;
  #pragma unroll
  for (int j=0;j<3;j++){
    v[j] = *(const float4*)(xr + lane*4 + j*256);
    s += v[j].x + v[j].y + v[j].z + v[j].w;
  }
  #pragma unroll
  for (int o=32;o;o>>=1) s += __shfl_xor(s, o);
  float mean = s * (1.f/768.f);
  float vs = 0.f;
  #pragma unroll
  for (int j=0;j<3;j++){
    float dx=v[j].x-mean, dy=v[j].y-mean, dz=v[j].z-mean, dw=v[j].w-mean;
    vs += dx*dx + dy*dy + dz*dz + dw*dw;
  }
  #pragma unroll
  for (int o=32;o;o>>=1) vs += __shfl_xor(vs, o);
  float rs = rsqrtf(vs*(1.f/768.f) + 1e-6f);
  bf16* orow = out + (size_t)row*768;
  #pragma unroll
  for (int j=0;j<3;j++){
    int d0 = lane*4 + j*256;
    float4 gv = *(const float4*)(g + d0);
    float4 bv = *(const float4*)(b + d0);
    uint2 pk;
    pk.x = pk2((v[j].x-mean)*rs*gv.x + bv.x, (v[j].y-mean)*rs*gv.y + bv.y);
    pk.y = pk2((v[j].z-mean)*rs*gv.z + bv.z, (v[j].w-mean)*rs*gv.w + bv.w);
    *(uint2*)(orow + d0) = pk;
  }
}

// ---------------- MFMA flash attention ----------------
__global__ __launch_bounds__(256) void attn_k(const bf16* __restrict__ qkv, bf16* __restrict__ o){
  __shared__ char Kc[2][32*128];
  __shared__ bf16 Vt[2][64][40];
  __shared__ bf16 Pl[4][32][40];

  const int blk = blockIdx.x;
  const int half = blk & 1, bh = blk >> 1;
  const int b = bh / 12, h = bh % 12;
  const int t = threadIdx.x, wave = t>>6, lane = t&63;
  const int qbase = half*128 + wave*32;
  const bf16* base = qkv + (size_t)b*NTOK*2304 + h*64;

  short8 qf[2][2];
  #pragma unroll
  for (int qt=0;qt<2;qt++){
    int row = qbase + qt*16 + (lane&15); row = row < NTOK ? row : NTOK-1;
    const bf16* qr = base + (size_t)row*2304 + (lane>>4)*8;
    qf[qt][0] = *(const short8*)(qr);
    qf[qt][1] = *(const short8*)(qr + 32);
  }

  f32x4 Oa[2][4];
  float mrow[2][4], srow[2][4];
  #pragma unroll
  for (int i=0;i<2;i++)
    #pragma unroll
    for (int j=0;j<4;j++){ Oa[i][j] = (f32x4){0.f,0.f,0.f,0.f}; }
  #pragma unroll
  for (int i=0;i<2;i++)
    #pragma unroll
    for (int j=0;j<4;j++){ mrow[i][j] = -1e30f; srow[i][j] = 0.f; }

  const int sr = t>>3, sc = (t&7)*8;
  auto ldK = [&](int c)->uint4{
    int kv = c*32 + sr; kv = kv < NTOK ? kv : NTOK-1;
    return *(const uint4*)(base + (size_t)kv*2304 + 768 + sc);
  };
  auto ldV = [&](int c)->uint4{
    int kv = c*32 + sr;
    uint4 r = {0,0,0,0};
    if (kv < NTOK) r = *(const uint4*)(base + (size_t)kv*2304 + 1536 + sc);
    return r;
  };
  auto wrK = [&](int buf, uint4 kvv){
    *(uint4*)(Kc[buf] + sr*128 + ((sc*2) ^ ((sr&7)<<4))) = kvv;
  };
  auto wrV = [&](int buf, uint4 vvv){
    union{ uint4 u; short s[8]; } w; w.u = vvv;
    #pragma unroll
    for (int j=0;j<8;j++) *(short*)&Vt[buf][sc+j][sr] = w.s[j];
  };

  { uint4 k0 = ldK(0), v0 = ldV(0); wrK(0,k0); wrV(0,v0); }
  __syncthreads();

  for (int c=0;c<7;c++){
    const int buf = c & 1;
    uint4 kn, vn; const bool pf = (c < 6);
    if (pf){ kn = ldK(c+1); vn = ldV(c+1); }

    f32x4 S[2][2];
    #pragma unroll
    for (int i=0;i<2;i++)
      #pragma unroll
      for (int j=0;j<2;j++) S[i][j] = (f32x4){0.f,0.f,0.f,0.f};
    #pragma unroll
    for (int kt=0;kt<2;kt++){
      int rk = kt*16 + (lane&15);
      const char* kb = Kc[buf] + rk*128;
      int swz = (rk&7)<<4;
      short8 b0 = *(const short8*)(kb + (((lane>>4)*16) ^ swz));
      short8 b1 = *(const short8*)(kb + ((64 + (lane>>4)*16) ^ swz));
      #pragma unroll
      for (int qt=0;qt<2;qt++){
        S[qt][kt] = __builtin_amdgcn_mfma_f32_16x16x32_bf16(qf[qt][0], b0, S[qt][kt],0,0,0);
        S[qt][kt] = __builtin_amdgcn_mfma_f32_16x16x32_bf16(qf[qt][1], b1, S[qt][kt],0,0,0);
      }
    }

    #pragma unroll
    for (int qt=0;qt<2;qt++){
      #pragma unroll
      for (int r=0;r<4;r++){
        float s0 = S[qt][0][r]*0.125f, s1 = S[qt][1][r]*0.125f;
        if (c == 6){
          if (192 + (lane&15) >= NTOK) s0 = -1e30f;
          s1 = -1e30f;
        }
        float mx = fmaxf(s0, s1);
        mx = fmaxf(mx, __shfl_xor(mx,1));
        mx = fmaxf(mx, __shfl_xor(mx,2));
        mx = fmaxf(mx, __shfl_xor(mx,4));
        mx = fmaxf(mx, __shfl_xor(mx,8));
        float mo = mrow[qt][r];
        float mn = fmaxf(mo, mx);
        float scl = __expf(mo - mn);
        mrow[qt][r] = mn;
        float p0 = __expf(s0 - mn), p1 = __expf(s1 - mn);
        srow[qt][r] = srow[qt][r]*scl + p0 + p1;
        #pragma unroll
        for (int dt=0;dt<4;dt++) Oa[qt][dt][r] *= scl;
        int pr = qt*16 + (lane>>4)*4 + r;
        Pl[wave][pr][lane&15]      = f2bf(p0);
        Pl[wave][pr][16+(lane&15)] = f2bf(p1);
      }
    }

    short8 vb[4];
    #pragma unroll
    for (int dt=0;dt<4;dt++)
      vb[dt] = *(const short8*)(&Vt[buf][dt*16+(lane&15)][(lane>>4)*8]);
    #pragma unroll
    for (int qt=0;qt<2;qt++){
      short8 pa = *(const short8*)(&Pl[wave][qt*16+(lane&15)][(lane>>4)*8]);
      #pragma unroll
      for (int dt=0;dt<4;dt++)
        Oa[qt][dt] = __builtin_amdgcn_mfma_f32_16x16x32_bf16(pa, vb[dt], Oa[qt][dt],0,0,0);
    }

    if (pf){ wrK(buf^1, kn); wrV(buf^1, vn); }
    __syncthreads();
  }

  #pragma unroll
  for (int qt=0;qt<2;qt++)
    #pragma unroll
    for (int r=0;r<4;r++){
      float s = srow[qt][r];
      s += __shfl_xor(s,1); s += __shfl_xor(s,2);
      s += __shfl_xor(s,4); s += __shfl_xor(s,8);
      srow[qt][r] = 1.f/s;
    }
  #pragma unroll
  for (int qt=0;qt<2;qt++){
    #pragma unroll
    for (int r=0;r<4;r++){
      int tok = qbase + qt*16 + (lane>>4)*4 + r;
      if (tok < NTOK){
        bf16* orow = o + ((size_t)(b*NTOK+tok))*768 + h*64 + (lane&15);
        float inv = srow[qt][r];
        #pragma unroll
        for (int dt=0;dt<4;dt++) orow[dt*16] = f2bf(Oa[qt][dt][r]*inv);
      }
    }
  }
}

// ---------------- mean-pool ----------------
__global__ void pool_k(const float* __restrict__ x, float* __restrict__ pooled){
  int idx = blockIdx.x*256 + threadIdx.x;
  if (idx >= 8*768) return;
  int b = idx / 768, d = idx % 768;
  float s = 0.f;
  for (int i=1;i<NTOK;i++) s += x[((size_t)(b*NTOK)+i)*768 + d];
  pooled[idx] = s * (1.f/196.f);
}

// ==================================================================
// Fused GEMM, 3-deep register pipeline + counted-vmcnt raw barriers.
//   WTYPE 1: W nibble-packed + scales[N,Kst/64]; WTYPE 2: W fp32 * wscale
//   LORA 1: extra K=64 chunk (A = sum of 4 u-partials, W = 0.25*Blora fp32)
//   OUTMODE 0: fp32 store at Cout + kz*kslab; 1: bf16; 2: C += gvec[n]*v
//   ACT 0 none, 1 gelu, 2 relu.  kz = blockIdx.z; k0 = kz*kiters.
// ==================================================================
template<int BM, int BN, int WTYPE, int LORA, int OUTMODE, int ACT>
__global__ __launch_bounds__(256) void gemm_k(
    const bf16* __restrict__ A, const void* __restrict__ W,
    const float* __restrict__ scales, const float* __restrict__ upart,
    const float* __restrict__ Blora, const float* __restrict__ bias,
    const float* __restrict__ gvec, void* __restrict__ Cout,
    int M, int N, int Kst, int kiters, size_t kslab, float wscale)
{
  constexpr int WCM = BM/2;           // wave tile M (2x2 wave grid)
  constexpr int WCN = BN/2;
  constexpr int FM  = WCM/16;         // 1 (BM=32) or 2 (BM=64)
  constexpr int FN  = WCN/16;
  constexpr int NA  = BM/32;          // A uint4 loads per thread
  constexpr int EPT = BN/4;
  constexpr int TPR = 64/EPT;
  constexpr int NLD = BN/16;
  constexpr int NPK = EPT/8;

  __shared__ char As[2][BM*128];
  __shared__ char Bs[2][BN*128];

  int mt, nt;
  {
    int gx = gridDim.x;
    int nwg = gx * gridDim.y;
    int bid = blockIdx.y * gx + blockIdx.x;
    int q8 = nwg >> 3, r8 = nwg & 7, xcd = bid & 7, idx = bid >> 3;
    int swz = (xcd < r8 ? xcd*(q8+1) : r8*(q8+1) + (xcd-r8)*q8) + idx;
    mt = swz / gx; nt = swz - mt*gx;
  }
  const int kz = blockIdx.z;
  const int k0 = kz * kiters;
  const int t = threadIdx.x, wave = t>>6, lane = t&63;
  const int wr = wave>>1, wc = wave&1;
  const int KT = kiters + (LORA ? 1 : 0);

  const int ar0 = t >> 3;             // 0..31
  const int acb = (t & 7) << 4;
  const int wrow = t / TPR;
  const int wko  = (t % TPR) * EPT;
  const int gnw  = nt*BN + wrow;

  f32x4 acc[FM][FN];
  #pragma unroll
  for (int i=0;i<FM;i++)
    #pragma unroll
    for (int j=0;j<FN;j++) acc[i][j] = (f32x4){0.f,0.f,0.f,0.f};

  auto loadA = [&](int it, uint4* av){
    #pragma unroll
    for (int i=0;i<NA;i++){
      int gm = mt*BM + ar0 + 32*i; gm = gm < M ? gm : M-1;
      if (LORA && it == kiters){
        const float* up = upart + (size_t)gm*64 + (acb>>1);
        float a[8];
        #pragma unroll
        for (int k=0;k<8;k++) a[k] = 0.f;
        #pragma unroll
        for (int pz=0; pz<4; pz++){
          const float* q = up + (size_t)pz*UROWS;
          float4 x0 = *(const float4*)q;
          float4 x1 = *(const float4*)(q+4);
          a[0]+=x0.x; a[1]+=x0.y; a[2]+=x0.z; a[3]+=x0.w;
          a[4]+=x1.x; a[5]+=x1.y; a[6]+=x1.z; a[7]+=x1.w;
        }
        uint4 r; r.x=pk2(a[0],a[1]); r.y=pk2(a[2],a[3]);
        r.z=pk2(a[4],a[5]); r.w=pk2(a[6],a[7]);
        av[i] = r;
      } else {
        av[i] = *(const uint4*)((const char*)A + ((size_t)gm*Kst + (((size_t)(k0+it))<<6))*2 + acb);
      }
    }
  };
  auto writeA = [&](int buf, uint4* av){
    #pragma unroll
    for (int i=0;i<NA;i++){
      int r = ar0 + 32*i;
      *(uint4*)(As[buf] + r*128 + (acb ^ ((r&7)<<4))) = av[i];
    }
  };
  auto loadWp = [&](int it, uint4& pw, float& sc){
    const unsigned* qp = (const unsigned*)W + (size_t)gnw*(Kst>>3) + ((size_t)(k0+it)<<3) + (wko>>3);
    if (NPK == 4) pw = *(const uint4*)qp;
    else { uint2 v = *(const uint2*)qp; pw.x = v.x; pw.y = v.y; pw.z = 0; pw.w = 0; }
    sc = scales[(size_t)gnw*(Kst>>6) + k0 + it];
  };
  auto writeWp = [&](int buf, uint4 pw, float sc){
    #pragma unroll
    for (int c=0;c<NPK;c++){
      unsigned u = (&pw.x)[c];
      float f[8];
      #pragma unroll
      for (int j=0;j<8;j++) f[j] = ((float)((u >> (4*j)) & 15u) - 7.5f) * sc;
      uint4 val;
      val.x = pk2(f[0],f[1]); val.y = pk2(f[2],f[3]);
      val.z = pk2(f[4],f[5]); val.w = pk2(f[6],f[7]);
      int cb = (wko + c*8)*2;
      *(uint4*)(Bs[buf] + wrow*128 + (cb ^ ((wrow&7)<<4))) = val;
    }
  };
  auto loadWf = [&](int it, uint4* wv, float& sc){
    if (LORA && it == kiters){
      const float* fp = Blora + (size_t)gnw*64 + wko;
      #pragma unroll
      for (int c=0;c<NLD;c++) wv[c] = *(const uint4*)(fp + c*4);
      sc = 0.25f;
    } else {
      const float* fp = (const float*)W + (size_t)gnw*Kst + ((k0+it)<<6) + wko;
      #pragma unroll
      for (int c=0;c<NLD;c++) wv[c] = *(const uint4*)(fp + c*4);
      sc = wscale;
    }
  };
  auto writeWf = [&](int buf, uint4* wv, float sc){
    #pragma unroll
    for (int c=0;c<EPT/8;c++){
      unsigned pkv[4];
      #pragma unroll
      for (int j=0;j<4;j++){
        float f0 = __uint_as_float(((const unsigned*)wv)[c*8 + 2*j])*sc;
        float f1 = __uint_as_float(((const unsigned*)wv)[c*8 + 2*j + 1])*sc;
        pkv[j] = pk2(f0, f1);
      }
      int cb = (wko + c*8)*2;
      uint4 val; val.x=pkv[0]; val.y=pkv[1]; val.z=pkv[2]; val.w=pkv[3];
      *(uint4*)(Bs[buf] + wrow*128 + (cb ^ ((wrow&7)<<4))) = val;
    }
  };

  auto loadS = [&](int it, uint4* av, uint4& pw, uint4* wv, float& sc){
    loadA(it, av);
    const bool packed = (WTYPE==1) && !(LORA && it==kiters);
    if (packed) loadWp(it, pw, sc);
    else        loadWf(it, wv, sc);
  };
  auto writeS = [&](int it, int buf, uint4* av, uint4& pw, uint4* wv, float sc){
    writeA(buf, av);
    const bool packed = (WTYPE==1) && !(LORA && it==kiters);
    if (packed) writeWp(buf, pw, sc);
    else        writeWf(buf, wv, sc);
  };

  const int lrow = lane & 15;
  const int lkb  = (lane >> 4) * 16;
  auto computeTile = [&](int buf){
    __builtin_amdgcn_s_setprio(1);
    #pragma unroll
    for (int kk=0; kk<2; kk++){
      short8 af[FM]; short8 bw[FN];
      #pragma unroll
      for (int f=0; f<FM; f++){
        int ra = wr*WCM + f*16 + lrow;
        af[f] = *(const short8*)(As[buf] + ra*128 + ((kk*64 + lkb) ^ ((ra&7)<<4)));
      }
      #pragma unroll
      for (int f=0; f<FN; f++){
        int rb = wc*WCN + f*16 + lrow;
        bw[f] = *(const short8*)(Bs[buf] + rb*128 + ((kk*64 + lkb) ^ ((rb&7)<<4)));
      }
      #pragma unroll
      for (int i=0;i<FM;i++)
        #pragma unroll
        for (int j=0;j<FN;j++)
          acc[i][j] = __builtin_amdgcn_mfma_f32_16x16x32_bf16(af[i], bw[j], acc[i][j], 0, 0, 0);
    }
    __builtin_amdgcn_s_setprio(0);
  };

  // ---- 3-deep pipeline: stage s loads issued at iter s-3; written at iter s-1 ----
  uint4 av0[NA], av1[NA], av2[NA];
  uint4 wv0[NLD], wv1[NLD], wv2[NLD];
  uint4 pw0, pw1, pw2;
  float sc0, sc1, sc2;

  loadS(0, av0, pw0, wv0, sc0);
  writeS(0, 0, av0, pw0, wv0, sc0);
  if (KT > 1) loadS(1, av1, pw1, wv1, sc1);
  if (KT > 2) loadS(2, av2, pw2, wv2, sc2);
  lds_barrier();

  int it = 0;
  while (true){
    if (it+3 < KT) loadS(it+3, av0, pw0, wv0, sc0);
    computeTile(it & 1);
    if (it+1 < KT) writeS(it+1, (it+1)&1, av1, pw1, wv1, sc1);
    lds_barrier();
    ++it; if (it >= KT) break;

    if (it+3 < KT) loadS(it+3, av1, pw1, wv1, sc1);
    computeTile(it & 1);
    if (it+1 < KT) writeS(it+1, (it+1)&1, av2, pw2, wv2, sc2);
    lds_barrier();
    ++it; if (it >= KT) break;

    if (it+3 < KT) loadS(it+3, av2, pw2, wv2, sc2);
    computeTile(it & 1);
    if (it+1 < KT) writeS(it+1, (it+1)&1, av0, pw0, wv0, sc0);
    lds_barrier();
    ++it; if (it >= KT) break;
  }

  // epilogue
  const int erow = (lane >> 4) * 4, ecol = lane & 15;
  #pragma unroll
  for (int i=0;i<FM;i++){
    #pragma unroll
    for (int j=0;j<FN;j++){
      int n = nt*BN + wc*WCN + j*16 + ecol;
      float bv = (bias != nullptr) ? bias[n] : 0.f;
      float gv = (OUTMODE==2) ? gvec[n] : 0.f;
      #pragma unroll
      for (int q=0; q<4; q++){
        int m = mt*BM + wr*WCM + i*16 + erow + q;
        if (m < M){
          float v = acc[i][j][q] + bv;
          if (ACT == 1) v = gelu_tanh(v);
          if (ACT == 2) v = fmaxf(v, 0.f);
          size_t off = (size_t)m*N + n;
          if (OUTMODE == 0)      ((float*)Cout)[(size_t)kz*kslab + off] = v;
          else if (OUTMODE == 1) ((bf16*)Cout)[off] = f2bf(v);
          else                   ((float*)Cout)[off] += gv * v;
        }
      }
    }
  }
}

// ===================================================================
extern "C" void kernel_launch(void* const* d_in, const int* in_sizes, int n_in,
                              void* d_out, int out_size, void* d_ws, size_t ws_size,
                              hipStream_t stream){
  (void)in_sizes; (void)n_in; (void)out_size; (void)ws_size;
  const float* img    = (const float*)d_in[0];
  const float* patchw = (const float*)d_in[1];
  const float* patchb = (const float*)d_in[2];
  const float* cls    = (const float*)d_in[3];
  const float* ln1g   = (const float*)d_in[4];
  const float* ln1b   = (const float*)d_in[5];
  const float* ln2g   = (const float*)d_in[6];
  const float* ln2b   = (const float*)d_in[7];
  const float* g1     = (const float*)d_in[8];
  const float* g2     = (const float*)d_in[9];
  const int*   qkvq   = (const int*)d_in[10];
  const float* qkvs   = (const float*)d_in[11];
  const float* qkvb   = (const float*)d_in[12];
  const float* aQ     = (const float*)d_in[13];
  const float* bQ     = (const float*)d_in[14];
  const int*   projq  = (const int*)d_in[15];
  const float* projs  = (const float*)d_in[16];
  const float* projb  = (const float*)d_in[17];
  const float* aP     = (const float*)d_in[18];
  const float* bP     = (const float*)d_in[19];
  const int*   fc1q   = (const int*)d_in[20];
  const float* fc1s   = (const float*)d_in[21];
  const float* fc1b   = (const float*)d_in[22];
  const int*   fc2q   = (const int*)d_in[23];
  const float* fc2s   = (const float*)d_in[24];
  const float* fc2b   = (const float*)d_in[25];
  const float* fcn_g  = (const float*)d_in[26];
  const float* fcn_b  = (const float*)d_in[27];
  const float* headw  = (const float*)d_in[28];
  const float* headb  = (const float*)d_in[29];
  float* out = (float*)d_out;

  char* wp = (char*)d_ws;
  auto alloc = [&](size_t bytes)->char* {
    char* r = wp; wp += (bytes + 255) & ~(size_t)255; return r;
  };
  float* x      = (float*)alloc((size_t)MTOK*768*4);
  bf16*  qkvo   = (bf16*) alloc((size_t)MTOK*2304*2);
  bf16*  h      = (bf16*) alloc((size_t)MTOK*768*2);
  bf16*  h1     = (bf16*) alloc((size_t)MTOK*3072*2);
  bf16*  ob     = (bf16*) alloc((size_t)MTOK*768*2);
  float* u_part = (float*)alloc((size_t)4*UROWS*4);
  bf16*  p      = (bf16*) alloc((size_t)MPATCH*768*2);
  float* tmp    = (float*)alloc((size_t)MTOK*768*4);
  float* pooled = (float*)alloc((size_t)8*768*4);
  bf16*  pooledb= (bf16*) alloc((size_t)8*768*2);
  unsigned* pq_qkv = (unsigned*)alloc((size_t)12*2304*768/2);
  unsigned* pq_proj= (unsigned*)alloc((size_t)12*768*768/2);
  unsigned* pq_fc1 = (unsigned*)alloc((size_t)12*3072*768/2);
  unsigned* pq_fc2 = (unsigned*)alloc((size_t)12*768*3072/2);

  const int GM32 = (MTOK + 31) / 32;   // 50

  pack_k<<<2048, 256, 0, stream>>>(qkvq, pq_qkv, 12*2304*768/8);
  pack_k<<<2048, 256, 0, stream>>>(projq, pq_proj, 12*768*768/8);
  pack_k<<<2048, 256, 0, stream>>>(fc1q, pq_fc1, 12*3072*768/8);
  pack_k<<<2048, 256, 0, stream>>>(fc2q, pq_fc2, 12*768*3072/8);

  patchify_k<<<(MPATCH*768 + 255)/256, 256, 0, stream>>>(img, p);
  gemm_k<32,64,2,0,0,0><<<dim3(768/64, (MPATCH+31)/32, 1), 256, 0, stream>>>(
      p, patchw, nullptr, nullptr, nullptr, patchb, nullptr, tmp,
      MPATCH, 768, 768, 12, 0, 1.f);
  assemble_k<<<(MTOK*768 + 255)/256, 256, 0, stream>>>(tmp, cls, x);

  for (int l=0; l<12; l++){
    const unsigned* qkvp_l = pq_qkv + (size_t)l*2304*768/8;
    const float*    qkvs_l = qkvs + (size_t)l*2304*12;
    const unsigned* projp_l= pq_proj + (size_t)l*768*768/8;
    const float*    projs_l= projs + (size_t)l*768*12;
    const unsigned* fc1p_l = pq_fc1 + (size_t)l*3072*768/8;
    const float*    fc1s_l = fc1s + (size_t)l*3072*12;
    const unsigned* fc2p_l = pq_fc2 + (size_t)l*768*3072/8;
    const float*    fc2s_l = fc2s + (size_t)l*768*48;

    // h = LN1(x)
    ln_k<<<(MTOK+3)/4, 256, 0, stream>>>(x, ln1g + l*768, ln1b + l*768, h, MTOK);
    // u partials = h @ aQ^T (split-K x4 via blockIdx.z)
    gemm_k<32,64,2,0,0,0><<<dim3(1, GM32, 4), 256, 0, stream>>>(
        h, aQ + (size_t)l*64*768, nullptr, nullptr, nullptr, nullptr, nullptr, u_part,
        MTOK, 64, 768, 3, UROWS, 1.f);
    // qkv = h @ dq(Wqkv)^T + qkv_b + 0.25*u@bQ^T  (bf16 out)
    gemm_k<32,128,1,1,1,0><<<dim3(2304/128, GM32, 1), 256, 0, stream>>>(
        h, qkvp_l, qkvs_l, u_part, bQ + (size_t)l*2304*64, qkvb + (size_t)l*2304,
        nullptr, qkvo, MTOK, 2304, 768, 12, 0, 1.f);
    // attention -> ob (bf16)
    attn_k<<<192, 256, 0, stream>>>(qkvo, ob);
    // u partials = ob @ aP^T
    gemm_k<32,64,2,0,0,0><<<dim3(1, GM32, 4), 256, 0, stream>>>(
        ob, aP + (size_t)l*64*768, nullptr, nullptr, nullptr, nullptr, nullptr, u_part,
        MTOK, 64, 768, 3, UROWS, 1.f);
    // x += g1 * (ob @ dq(Wproj)^T + proj_b + 0.25*u@bP^T)
    gemm_k<32,64,1,1,2,0><<<dim3(768/64, GM32, 1), 256, 0, stream>>>(
        ob, projp_l, projs_l, u_part, bP + (size_t)l*768*64, projb + (size_t)l*768,
        g1 + l*768, x, MTOK, 768, 768, 12, 0, 1.f);

    // h = LN2(x); h1 = gelu(h @ dq(Wfc1)^T + fc1_b)
    ln_k<<<(MTOK+3)/4, 256, 0, stream>>>(x, ln2g + l*768, ln2b + l*768, h, MTOK);
    gemm_k<32,128,1,0,1,1><<<dim3(3072/128, GM32, 1), 256, 0, stream>>>(
        h, fc1p_l, fc1s_l, nullptr, nullptr, fc1b + (size_t)l*3072,
        nullptr, h1, MTOK, 3072, 768, 12, 0, 1.f);
    // x += g2 * (h1 @ dq(Wfc2)^T + fc2_b)   (fused residual, full K in-block)
    gemm_k<32,64,1,0,2,0><<<dim3(768/64, GM32, 1), 256, 0, stream>>>(
        h1, fc2p_l, fc2s_l, nullptr, nullptr, fc2b + (size_t)l*768,
        g2 + l*768, x, MTOK, 768, 3072, 48, 0, 1.f);
  }

  pool_k<<<(8*768 + 255)/256, 256, 0, stream>>>(x, pooled);
  ln_k<<<2, 256, 0, stream>>>(pooled, fcn_g, fcn_b, pooledb, 8);
  gemm_k<32,128,2,0,0,2><<<dim3(512/128, 1, 1), 256, 0, stream>>>(
      pooledb, headw, nullptr, nullptr, nullptr, headb, nullptr, out,
      8, 512, 768, 12, 0, 1.f);
}